// Round 1
// baseline (255.485 us; speedup 1.0000x reference)
//
#include <hip/hip_runtime.h>

#define N_NODES 50000
#define N_EDGES 800000
#define C 128
#define BN_EPS 1e-5f
#define BSHIFT 7                              // 128 nodes per bucket
#define NBUCK ((N_NODES + 127) >> BSHIFT)     // 391
#define EPB 4096                              // edges per block (edge-pass kernels)
#define A_BLOCKS ((N_EDGES + EPB - 1) / EPB)  // 196

typedef __attribute__((ext_vector_type(8))) short bf16x8;
typedef __attribute__((ext_vector_type(4))) float f32x4;

__device__ __forceinline__ unsigned pack_bf16x2(float a, float b) {
    unsigned ua = __float_as_uint(a);
    ua = (ua + 0x7FFFu + ((ua >> 16) & 1u)) >> 16;   // RNE
    unsigned ub = __float_as_uint(b);
    ub = (ub + 0x7FFFu + ((ub >> 16) & 1u)) >> 16;
    return ua | (ub << 16);
}

__device__ __forceinline__ unsigned short bf16_1(float a) {
    unsigned u = __float_as_uint(a);
    return (unsigned short)((u + 0x7FFFu + ((u >> 16) & 1u)) >> 16);
}

__device__ __forceinline__ float blo(unsigned u) { return __uint_as_float(u << 16); }
__device__ __forceinline__ float bhi(unsigned u) { return __uint_as_float(u & 0xFFFF0000u); }

// ---- pass 1: per-node degree via global atomics (16-way avg contention),
//      per-block LDS bucket histogram -> btot, block 0 builds coalesced bf16 W ----
// WTn layout (dword index i = ((nt*4+kt)*64 + q*16+m)*4 + j):
//   pack( W[kt*32+q*8+2j][nt*16+m], W[kt*32+q*8+2j+1][nt*16+m] )
// so gemm's B fragment for (nt,kt) is uint4 at [(nt*4+kt)*64 + lane] -- coalesced.
__global__ void __launch_bounds__(256) k_deg(const int* __restrict__ col,
                                             int* __restrict__ cnt,
                                             int* __restrict__ btot,
                                             const float* __restrict__ W,
                                             unsigned* __restrict__ WTn) {
    __shared__ int hist[NBUCK];
    for (int i = threadIdx.x; i < NBUCK; i += 256) hist[i] = 0;
    __syncthreads();
    int e0 = blockIdx.x * EPB;
    int e1 = e0 + EPB; if (e1 > N_EDGES) e1 = N_EDGES;
    for (int e = e0 + threadIdx.x; e < e1; e += 256) {
        int d = col[e];
        atomicAdd(&cnt[d], 1);
        atomicAdd(&hist[d >> BSHIFT], 1);
    }
    if (blockIdx.x == 0) {
#pragma unroll
        for (int it = 0; it < 32; ++it) {
            int i = threadIdx.x + (it << 8);
            int j = i & 3, l = (i >> 2) & 63, kt = (i >> 8) & 3, nt = i >> 10;
            int m = l & 15, q = l >> 4;
            int kr = kt * 32 + q * 8 + 2 * j;
            int n = nt * 16 + m;
            WTn[i] = pack_bf16x2(W[kr * C + n], W[(kr + 1) * C + n]);
        }
    }
    __syncthreads();
    for (int i = threadIdx.x; i < NBUCK; i += 256)
        if (hist[i]) atomicAdd(&btot[i], hist[i]);
}

// ---- scan 391 bucket totals -> bStart (exclusive) ----
__global__ void __launch_bounds__(512) k_scanb(const int* __restrict__ btot,
                                               int* __restrict__ bStart,
                                               int* __restrict__ offs) {
    __shared__ int ws[8];
    int t = threadIdx.x, lane = t & 63, wid = t >> 6;
    int v = (t < NBUCK) ? btot[t] : 0;
    int sc = v;
#pragma unroll
    for (int d = 1; d < 64; d <<= 1) {
        int u = __shfl_up(sc, d, 64);
        if (lane >= d) sc += u;
    }
    if (lane == 63) ws[wid] = sc;
    __syncthreads();
    int add = 0;
    for (int w = 0; w < wid; ++w) add += ws[w];
    if (t < NBUCK) bStart[t] = add + sc - v;
    if (t == 0) { bStart[NBUCK] = N_EDGES; offs[N_NODES] = N_EDGES; }
}

// ---- per-bucket local scan of cnt -> absolute offs, cur ----
__global__ void __launch_bounds__(128) k_offs(const int* __restrict__ cnt,
                                              const int* __restrict__ bStart,
                                              int* __restrict__ offs,
                                              int* __restrict__ cur) {
    __shared__ int w0;
    int b = blockIdx.x, t = threadIdx.x, lane = t & 63;
    int n = (b << BSHIFT) + t;
    int v = (n < N_NODES) ? cnt[n] : 0;
    int sc = v;
#pragma unroll
    for (int d = 1; d < 64; d <<= 1) {
        int u = __shfl_up(sc, d, 64);
        if (lane >= d) sc += u;
    }
    if (t == 63) w0 = sc;
    __syncthreads();
    int ex = sc - v + ((t >= 64) ? w0 : 0) + bStart[b];
    if (n < N_NODES) { offs[n] = ex; cur[n] = ex; }
}

// ---- pass 2: scatter source ids into CSR slots via atomic cursors ----
__global__ void __launch_bounds__(256) k_scatter(const int* __restrict__ row,
                                                 const int* __restrict__ col,
                                                 int* __restrict__ cur,
                                                 unsigned short* __restrict__ srcs) {
    int e0 = blockIdx.x * EPB;
    int e1 = e0 + EPB; if (e1 > N_EDGES) e1 = N_EDGES;
    for (int e = e0 + threadIdx.x; e < e1; e += 256) {
        int d = col[e];
        int p = atomicAdd(&cur[d], 1);
        srcs[p] = (unsigned short)row[e];
    }
}

// ---- g(bf16) = dinv[row]*(x@W) via MFMA 16x16x32 bf16; coalesced B loads ----
__global__ void __launch_bounds__(256) k_gemm(const float* __restrict__ x,
                                              const unsigned* __restrict__ WTn,
                                              const int* __restrict__ cnt,
                                              unsigned short* __restrict__ g) {
    __shared__ unsigned xs[64 * 68];  // 64 rows x 68 dwords (128 bf16 + pad)
    int tid = threadIdx.x;
    int r0 = blockIdx.x * 64;
    const float4* x4 = (const float4*)x;
#pragma unroll
    for (int it = 0; it < 8; ++it) {
        int i = tid + (it << 8);
        int row = i >> 5, c4 = i & 31;
        float4 v = {0.f, 0.f, 0.f, 0.f};
        if (r0 + row < N_NODES) v = x4[(size_t)(r0 + row) * 32 + c4];
        xs[row * 68 + c4 * 2]     = pack_bf16x2(v.x, v.y);
        xs[row * 68 + c4 * 2 + 1] = pack_bf16x2(v.z, v.w);
    }
    __syncthreads();
    int wave = tid >> 6, lane = tid & 63;
    int r0w = r0 + wave * 16;
    if (r0w >= N_NODES) return;
    int m = lane & 15, q = lane >> 4;
    bf16x8 afrag[4];
#pragma unroll
    for (int kt = 0; kt < 4; ++kt)
        afrag[kt] = *(const bf16x8*)&xs[(wave * 16 + m) * 68 + kt * 16 + q * 4];
    const uint4* B4 = (const uint4*)WTn;
    f32x4 acc[8];
#pragma unroll
    for (int nt = 0; nt < 8; ++nt)
        acc[nt][0] = acc[nt][1] = acc[nt][2] = acc[nt][3] = 0.f;
#pragma unroll
    for (int nt = 0; nt < 8; ++nt) {
#pragma unroll
        for (int kt = 0; kt < 4; ++kt) {
            uint4 braw = B4[(nt * 4 + kt) * 64 + lane];   // coalesced 1 KB/instr
            bf16x8 bfrag = __builtin_bit_cast(bf16x8, braw);
            acc[nt] = __builtin_amdgcn_mfma_f32_16x16x32_bf16(afrag[kt], bfrag, acc[nt], 0, 0, 0);
        }
    }
    int rb = r0w + q * 4;
    float dv[4];
#pragma unroll
    for (int reg = 0; reg < 4; ++reg) dv[reg] = rsqrtf((float)cnt[rb + reg] + 1.f);
#pragma unroll
    for (int nt = 0; nt < 8; ++nt) {
        int cbase = nt * 16 + m;
#pragma unroll
        for (int reg = 0; reg < 4; ++reg)
            g[(size_t)(rb + reg) * C + cbase] = bf16_1(acc[nt][reg] * dv[reg]);
    }
}

// ---- gather: 16 lanes per node, 4 nodes per wave, uint4 row segments ----
__global__ void __launch_bounds__(256) k_gather(const int* __restrict__ offs,
                                                const unsigned short* __restrict__ srcs,
                                                const uint4* __restrict__ g4,
                                                float* __restrict__ agg) {
    int t = threadIdx.x;
    int node = blockIdx.x * 16 + (t >> 4);
    if (node >= N_NODES) return;
    int l = t & 15;          // lane within quarter
    int qb = t & 48;         // quarter base within wave (0,16,32,48)
    int beg = offs[node], end = offs[node + 1];
    uint4 u = g4[(size_t)node * 16 + l];  // self-loop term
    float a0[8], a1[8], a2[8], a3[8];
    a0[0] = blo(u.x); a0[1] = bhi(u.x); a0[2] = blo(u.y); a0[3] = bhi(u.y);
    a0[4] = blo(u.z); a0[5] = bhi(u.z); a0[6] = blo(u.w); a0[7] = bhi(u.w);
#pragma unroll
    for (int i = 0; i < 8; ++i) { a1[i] = 0.f; a2[i] = 0.f; a3[i] = 0.f; }
    for (int base = beg; base < end; base += 16) {
        int m = end - base; if (m > 16) m = 16;
        int sv = (base + l < end) ? (int)srcs[base + l] : 0;  // 16-wide batch
        int j = 0;
        for (; j + 3 < m; j += 4) {
            int s0 = __shfl(sv, qb + j, 64);
            int s1 = __shfl(sv, qb + j + 1, 64);
            int s2 = __shfl(sv, qb + j + 2, 64);
            int s3 = __shfl(sv, qb + j + 3, 64);
            uint4 v0 = g4[(size_t)s0 * 16 + l];
            uint4 v1 = g4[(size_t)s1 * 16 + l];
            uint4 v2 = g4[(size_t)s2 * 16 + l];
            uint4 v3 = g4[(size_t)s3 * 16 + l];
            a0[0] += blo(v0.x); a0[1] += bhi(v0.x); a0[2] += blo(v0.y); a0[3] += bhi(v0.y);
            a0[4] += blo(v0.z); a0[5] += bhi(v0.z); a0[6] += blo(v0.w); a0[7] += bhi(v0.w);
            a1[0] += blo(v1.x); a1[1] += bhi(v1.x); a1[2] += blo(v1.y); a1[3] += bhi(v1.y);
            a1[4] += blo(v1.z); a1[5] += bhi(v1.z); a1[6] += blo(v1.w); a1[7] += bhi(v1.w);
            a2[0] += blo(v2.x); a2[1] += bhi(v2.x); a2[2] += blo(v2.y); a2[3] += bhi(v2.y);
            a2[4] += blo(v2.z); a2[5] += bhi(v2.z); a2[6] += blo(v2.w); a2[7] += bhi(v2.w);
            a3[0] += blo(v3.x); a3[1] += bhi(v3.x); a3[2] += blo(v3.y); a3[3] += bhi(v3.y);
            a3[4] += blo(v3.z); a3[5] += bhi(v3.z); a3[6] += blo(v3.w); a3[7] += bhi(v3.w);
        }
        for (; j < m; ++j) {
            int s0 = __shfl(sv, qb + j, 64);
            uint4 v0 = g4[(size_t)s0 * 16 + l];
            a0[0] += blo(v0.x); a0[1] += bhi(v0.x); a0[2] += blo(v0.y); a0[3] += bhi(v0.y);
            a0[4] += blo(v0.z); a0[5] += bhi(v0.z); a0[6] += blo(v0.w); a0[7] += bhi(v0.w);
        }
    }
    float dt = rsqrtf((float)(end - beg) + 1.f);
    float4 o0, o1;
    o0.x = (a0[0] + a1[0] + a2[0] + a3[0]) * dt;
    o0.y = (a0[1] + a1[1] + a2[1] + a3[1]) * dt;
    o0.z = (a0[2] + a1[2] + a2[2] + a3[2]) * dt;
    o0.w = (a0[3] + a1[3] + a2[3] + a3[3]) * dt;
    o1.x = (a0[4] + a1[4] + a2[4] + a3[4]) * dt;
    o1.y = (a0[5] + a1[5] + a2[5] + a3[5]) * dt;
    o1.z = (a0[6] + a1[6] + a2[6] + a3[6]) * dt;
    o1.w = (a0[7] + a1[7] + a2[7] + a3[7]) * dt;
    float4* out = (float4*)(agg + (size_t)node * C + l * 8);
    out[0] = o0; out[1] = o1;
}

// ---- per-channel sum / sumsq over nodes ----
__global__ void __launch_bounds__(256) k_stats(const float* __restrict__ agg,
                                               float* __restrict__ sums,
                                               float* __restrict__ sumsq) {
    int tx = threadIdx.x;
    int r = blockIdx.x * 8 + threadIdx.y;
    int stride = gridDim.x * 8;
    const float4* a4 = (const float4*)agg;
    float4 s = {0,0,0,0}, q = {0,0,0,0};
    for (; r < N_NODES; r += stride) {
        float4 v = a4[(size_t)r * 32 + tx];
        s.x += v.x; s.y += v.y; s.z += v.z; s.w += v.w;
        q.x += v.x * v.x; q.y += v.y * v.y; q.z += v.z * v.z; q.w += v.w * v.w;
    }
    __shared__ float4 ls[8][32], lq[8][32];
    ls[threadIdx.y][tx] = s; lq[threadIdx.y][tx] = q;
    __syncthreads();
    if (threadIdx.y == 0) {
        for (int w = 1; w < 8; ++w) {
            float4 v = ls[w][tx], u = lq[w][tx];
            s.x += v.x; s.y += v.y; s.z += v.z; s.w += v.w;
            q.x += u.x; q.y += u.y; q.z += u.z; q.w += u.w;
        }
        int c = tx * 4;
        atomicAdd(&sums[c + 0], s.x); atomicAdd(&sums[c + 1], s.y);
        atomicAdd(&sums[c + 2], s.z); atomicAdd(&sums[c + 3], s.w);
        atomicAdd(&sumsq[c + 0], q.x); atomicAdd(&sumsq[c + 1], q.y);
        atomicAdd(&sumsq[c + 2], q.z); atomicAdd(&sumsq[c + 3], q.w);
    }
}

// ---- y = relu(agg*scale + shift); bias cancels in BN ----
__global__ void __launch_bounds__(256) k_final(float* __restrict__ agg,
                                               const float* __restrict__ sums,
                                               const float* __restrict__ sumsq,
                                               const float* __restrict__ gamma,
                                               const float* __restrict__ beta) {
    __shared__ float sc_s[C], sh_s[C];
    int tid = threadIdx.x;
    if (tid < C) {
        float mean = sums[tid] * (1.0f / N_NODES);
        float var = sumsq[tid] * (1.0f / N_NODES) - mean * mean;
        float sc = gamma[tid] * rsqrtf(var + BN_EPS);
        sc_s[tid] = sc;
        sh_s[tid] = beta[tid] - mean * sc;
    }
    __syncthreads();
    int i = blockIdx.x * 256 + tid;
    if (i >= N_NODES * 32) return;
    int c = (i & 31) * 4;
    float4 v = ((float4*)agg)[i];
    v.x = fmaxf(v.x * sc_s[c + 0] + sh_s[c + 0], 0.f);
    v.y = fmaxf(v.y * sc_s[c + 1] + sh_s[c + 1], 0.f);
    v.z = fmaxf(v.z * sc_s[c + 2] + sh_s[c + 2], 0.f);
    v.w = fmaxf(v.w * sc_s[c + 3] + sh_s[c + 3], 0.f);
    ((float4*)agg)[i] = v;
}

extern "C" void kernel_launch(void* const* d_in, const int* in_sizes, int n_in,
                              void* d_out, int out_size, void* d_ws, size_t ws_size,
                              hipStream_t stream) {
    const float* x     = (const float*)d_in[0];
    const float* W     = (const float*)d_in[1];
    // d_in[2] = bias: cancels in BatchNorm, unused
    const float* gamma = (const float*)d_in[3];
    const float* beta  = (const float*)d_in[4];
    const int*   eidx  = (const int*)d_in[5];
    const int* row = eidx;
    const int* col = eidx + N_EDGES;

    float* agg = (float*)d_out;  // [N, C], finalized in place

    // workspace layout
    unsigned* g = (unsigned*)d_ws;                               // [N*64] bf16x2 rows
    unsigned short* srcs = (unsigned short*)(g + (size_t)N_NODES * 64); // [E] u16
    int*   cnt    = (int*)(srcs + N_EDGES);                      // [N]      -- zeroed
    int*   btot   = cnt + N_NODES;                               // [NBUCK]  -- zeroed
    float* sums   = (float*)(btot + NBUCK);                      // [C]      -- zeroed
    float* sumsq  = sums + C;                                    // [C]      -- zeroed
    int*   offs   = (int*)(sumsq + C);                           // [N+1]
    int*   cur    = offs + N_NODES + 1;                          // [N]
    int*   bStart = cur + N_NODES;                               // [NBUCK+1]
    unsigned* WTn = (unsigned*)(bStart + NBUCK + 1);             // [8192] bf16x2 (W, MFMA-B layout)

    hipMemsetAsync(cnt, 0, (size_t)(N_NODES + NBUCK + 2 * C) * sizeof(int), stream);
    k_deg<<<A_BLOCKS, 256, 0, stream>>>(col, cnt, btot, W, WTn);
    k_scanb<<<1, 512, 0, stream>>>(btot, bStart, offs);
    k_offs<<<NBUCK, 128, 0, stream>>>(cnt, bStart, offs, cur);
    k_scatter<<<A_BLOCKS, 256, 0, stream>>>(row, col, cur, srcs);
    k_gemm<<<(N_NODES + 63) / 64, 256, 0, stream>>>(x, WTn, cnt, (unsigned short*)g);
    k_gather<<<(N_NODES + 15) / 16, 256, 0, stream>>>(offs, srcs, (const uint4*)g, agg);
    k_stats<<<256, dim3(32, 8), 0, stream>>>(agg, sums, sumsq);
    k_final<<<(N_NODES * 32 + 255) / 256, 256, 0, stream>>>(agg, sums, sumsq, gamma, beta);
}

// Round 2
// 202.300 us; speedup vs baseline: 1.2629x; 1.2629x over previous
//
#include <hip/hip_runtime.h>

#define N_NODES 50000
#define N_EDGES 800000
#define C 128
#define BN_EPS 1e-5f
#define BSHIFT 7                              // 128 nodes per bucket
#define NBUCK ((N_NODES + 127) >> BSHIFT)     // 391
#define SLOT 4096                             // fixed bEdges capacity per bucket (mean 2046, +45 sigma)
#define EPB 4096                              // edges per block (edge-pass kernels)
#define A_BLOCKS ((N_EDGES + EPB - 1) / EPB)  // 196

typedef __attribute__((ext_vector_type(8))) short bf16x8;
typedef __attribute__((ext_vector_type(4))) float f32x4;

__device__ __forceinline__ unsigned pack_bf16x2(float a, float b) {
    unsigned ua = __float_as_uint(a);
    ua = (ua + 0x7FFFu + ((ua >> 16) & 1u)) >> 16;   // RNE
    unsigned ub = __float_as_uint(b);
    ub = (ub + 0x7FFFu + ((ub >> 16) & 1u)) >> 16;
    return ua | (ub << 16);
}

__device__ __forceinline__ unsigned short bf16_1(float a) {
    unsigned u = __float_as_uint(a);
    return (unsigned short)((u + 0x7FFFu + ((u >> 16) & 1u)) >> 16);
}

__device__ __forceinline__ float blo(unsigned u) { return __uint_as_float(u << 16); }
__device__ __forceinline__ float bhi(unsigned u) { return __uint_as_float(u & 0xFFFF0000u); }

// ---- single-pass bucket scatter: LDS histogram -> one cursor atomic per
//      (block,bucket) -> scatter packed edges into fixed per-bucket slots.
//      Block 0 also builds the MFMA-B-layout bf16 W.
// WTn layout (dword index i = ((nt*4+kt)*64 + q*16+m)*4 + j):
//   pack( W[kt*32+q*8+2j][nt*16+m], W[kt*32+q*8+2j+1][nt*16+m] )
// so gemm's B fragment for (nt,kt) is uint4 at [(nt*4+kt)*64 + lane] -- coalesced.
__global__ void __launch_bounds__(256) k_scat(const int* __restrict__ row,
                                              const int* __restrict__ col,
                                              int* __restrict__ bcur,
                                              unsigned* __restrict__ bEdges,
                                              const float* __restrict__ W,
                                              unsigned* __restrict__ WTn) {
    __shared__ int hist[NBUCK];
    __shared__ int lbase[NBUCK];
    int tid = threadIdx.x;
    for (int i = tid; i < NBUCK; i += 256) hist[i] = 0;
    __syncthreads();
    int e0 = blockIdx.x * EPB;
    int e1 = e0 + EPB; if (e1 > N_EDGES) e1 = N_EDGES;
    for (int e = e0 + tid; e < e1; e += 256)
        atomicAdd(&hist[col[e] >> BSHIFT], 1);
    if (blockIdx.x == 0) {
#pragma unroll
        for (int it = 0; it < 32; ++it) {
            int i = tid + (it << 8);
            int j = i & 3, l = (i >> 2) & 63, kt = (i >> 8) & 3, nt = i >> 10;
            int m = l & 15, q = l >> 4;
            int kr = kt * 32 + q * 8 + 2 * j;
            int n = nt * 16 + m;
            WTn[i] = pack_bf16x2(W[kr * C + n], W[(kr + 1) * C + n]);
        }
    }
    __syncthreads();
    for (int i = tid; i < NBUCK; i += 256) {
        int h = hist[i];
        lbase[i] = h ? atomicAdd(&bcur[i], h) : 0;  // one device atomic per (block,bucket)
        hist[i] = 0;                                // reuse as in-block cursor
    }
    __syncthreads();
    for (int e = e0 + tid; e < e1; e += 256) {
        int d = col[e];
        int b = d >> BSHIFT;
        int r = atomicAdd(&hist[b], 1);
        bEdges[b * SLOT + lbase[b] + r] = (unsigned)row[e] | ((unsigned)d << 16);
    }
}

// ---- per-bucket: derive global offset by reducing bucket counts, node
//      histogram + scan -> offs/cnt, scatter srcs into compact CSR ----
__global__ void __launch_bounds__(256) k_bsort(const unsigned* __restrict__ bEdges,
                                               const int* __restrict__ bcur,
                                               int* __restrict__ offs,
                                               int* __restrict__ cnt,
                                               unsigned short* __restrict__ srcs) {
    __shared__ int red[256];
    __shared__ int h[128];
    __shared__ int wtot;
    int tid = threadIdx.x;
    int b = blockIdx.x;
    // e0 = sum_{i<b} bcur[i]  (L2-hot 1.6 KB, <=2 loads/thread)
    int part = 0;
    for (int i = tid; i < b; i += 256) part += bcur[i];
    red[tid] = part;
    if (tid < 128) h[tid] = 0;
    __syncthreads();
#pragma unroll
    for (int s = 128; s > 0; s >>= 1) {
        if (tid < s) red[tid] += red[tid + s];
        __syncthreads();
    }
    int e0 = red[0];
    int c = bcur[b];
    int n0 = b << BSHIFT;
    int nn = N_NODES - n0; if (nn > 128) nn = 128;
    const unsigned* slot = bEdges + (size_t)b * SLOT;
    for (int e = tid; e < c; e += 256)
        atomicAdd(&h[(int)(slot[e] >> 16) - n0], 1);
    __syncthreads();
    int v = 0, sc = 0;
    if (tid < 128) {
        int lane = tid & 63;
        v = h[tid];
        sc = v;
#pragma unroll
        for (int d = 1; d < 64; d <<= 1) {
            int u = __shfl_up(sc, d, 64);
            if (lane >= d) sc += u;
        }
        if (tid == 63) wtot = sc;
    }
    __syncthreads();
    if (tid < 128) {
        int ex = sc - v + ((tid >= 64) ? wtot : 0);
        if (tid < nn) { offs[n0 + tid] = e0 + ex; cnt[n0 + tid] = v; }
        h[tid] = ex;  // reuse as cursor
    }
    __syncthreads();
    for (int e = tid; e < c; e += 256) {
        unsigned pe = slot[e];
        int r = atomicAdd(&h[(int)(pe >> 16) - n0], 1);
        srcs[e0 + r] = (unsigned short)(pe & 0xFFFFu);
    }
    if (b == NBUCK - 1 && tid == 0) offs[N_NODES] = N_EDGES;
}

// ---- g(bf16) = dinv[row]*(x@W) via MFMA 16x16x32 bf16; coalesced B loads ----
__global__ void __launch_bounds__(256) k_gemm(const float* __restrict__ x,
                                              const unsigned* __restrict__ WTn,
                                              const int* __restrict__ cnt,
                                              unsigned short* __restrict__ g) {
    __shared__ unsigned xs[64 * 68];  // 64 rows x 68 dwords (128 bf16 + pad)
    int tid = threadIdx.x;
    int r0 = blockIdx.x * 64;
    const float4* x4 = (const float4*)x;
#pragma unroll
    for (int it = 0; it < 8; ++it) {
        int i = tid + (it << 8);
        int row = i >> 5, c4 = i & 31;
        float4 v = {0.f, 0.f, 0.f, 0.f};
        if (r0 + row < N_NODES) v = x4[(size_t)(r0 + row) * 32 + c4];
        xs[row * 68 + c4 * 2]     = pack_bf16x2(v.x, v.y);
        xs[row * 68 + c4 * 2 + 1] = pack_bf16x2(v.z, v.w);
    }
    __syncthreads();
    int wave = tid >> 6, lane = tid & 63;
    int r0w = r0 + wave * 16;
    if (r0w >= N_NODES) return;
    int m = lane & 15, q = lane >> 4;
    bf16x8 afrag[4];
#pragma unroll
    for (int kt = 0; kt < 4; ++kt)
        afrag[kt] = *(const bf16x8*)&xs[(wave * 16 + m) * 68 + kt * 16 + q * 4];
    const uint4* B4 = (const uint4*)WTn;
    f32x4 acc[8];
#pragma unroll
    for (int nt = 0; nt < 8; ++nt)
        acc[nt][0] = acc[nt][1] = acc[nt][2] = acc[nt][3] = 0.f;
#pragma unroll
    for (int nt = 0; nt < 8; ++nt) {
#pragma unroll
        for (int kt = 0; kt < 4; ++kt) {
            uint4 braw = B4[(nt * 4 + kt) * 64 + lane];   // coalesced 1 KB/instr
            bf16x8 bfrag = __builtin_bit_cast(bf16x8, braw);
            acc[nt] = __builtin_amdgcn_mfma_f32_16x16x32_bf16(afrag[kt], bfrag, acc[nt], 0, 0, 0);
        }
    }
    int rb = r0w + q * 4;
    float dv[4];
#pragma unroll
    for (int reg = 0; reg < 4; ++reg) dv[reg] = rsqrtf((float)cnt[rb + reg] + 1.f);
#pragma unroll
    for (int nt = 0; nt < 8; ++nt) {
        int cbase = nt * 16 + m;
#pragma unroll
        for (int reg = 0; reg < 4; ++reg)
            g[(size_t)(rb + reg) * C + cbase] = bf16_1(acc[nt][reg] * dv[reg]);
    }
}

// ---- gather: 16 lanes per node, 4 nodes per wave, uint4 row segments ----
__global__ void __launch_bounds__(256) k_gather(const int* __restrict__ offs,
                                                const unsigned short* __restrict__ srcs,
                                                const uint4* __restrict__ g4,
                                                float* __restrict__ agg) {
    int t = threadIdx.x;
    int node = blockIdx.x * 16 + (t >> 4);
    if (node >= N_NODES) return;
    int l = t & 15;          // lane within quarter
    int qb = t & 48;         // quarter base within wave (0,16,32,48)
    int beg = offs[node], end = offs[node + 1];
    uint4 u = g4[(size_t)node * 16 + l];  // self-loop term
    float a0[8], a1[8], a2[8], a3[8];
    a0[0] = blo(u.x); a0[1] = bhi(u.x); a0[2] = blo(u.y); a0[3] = bhi(u.y);
    a0[4] = blo(u.z); a0[5] = bhi(u.z); a0[6] = blo(u.w); a0[7] = bhi(u.w);
#pragma unroll
    for (int i = 0; i < 8; ++i) { a1[i] = 0.f; a2[i] = 0.f; a3[i] = 0.f; }
    for (int base = beg; base < end; base += 16) {
        int m = end - base; if (m > 16) m = 16;
        int sv = (base + l < end) ? (int)srcs[base + l] : 0;  // 16-wide batch
        int j = 0;
        for (; j + 3 < m; j += 4) {
            int s0 = __shfl(sv, qb + j, 64);
            int s1 = __shfl(sv, qb + j + 1, 64);
            int s2 = __shfl(sv, qb + j + 2, 64);
            int s3 = __shfl(sv, qb + j + 3, 64);
            uint4 v0 = g4[(size_t)s0 * 16 + l];
            uint4 v1 = g4[(size_t)s1 * 16 + l];
            uint4 v2 = g4[(size_t)s2 * 16 + l];
            uint4 v3 = g4[(size_t)s3 * 16 + l];
            a0[0] += blo(v0.x); a0[1] += bhi(v0.x); a0[2] += blo(v0.y); a0[3] += bhi(v0.y);
            a0[4] += blo(v0.z); a0[5] += bhi(v0.z); a0[6] += blo(v0.w); a0[7] += bhi(v0.w);
            a1[0] += blo(v1.x); a1[1] += bhi(v1.x); a1[2] += blo(v1.y); a1[3] += bhi(v1.y);
            a1[4] += blo(v1.z); a1[5] += bhi(v1.z); a1[6] += blo(v1.w); a1[7] += bhi(v1.w);
            a2[0] += blo(v2.x); a2[1] += bhi(v2.x); a2[2] += blo(v2.y); a2[3] += bhi(v2.y);
            a2[4] += blo(v2.z); a2[5] += bhi(v2.z); a2[6] += blo(v2.w); a2[7] += bhi(v2.w);
            a3[0] += blo(v3.x); a3[1] += bhi(v3.x); a3[2] += blo(v3.y); a3[3] += bhi(v3.y);
            a3[4] += blo(v3.z); a3[5] += bhi(v3.z); a3[6] += blo(v3.w); a3[7] += bhi(v3.w);
        }
        for (; j < m; ++j) {
            int s0 = __shfl(sv, qb + j, 64);
            uint4 v0 = g4[(size_t)s0 * 16 + l];
            a0[0] += blo(v0.x); a0[1] += bhi(v0.x); a0[2] += blo(v0.y); a0[3] += bhi(v0.y);
            a0[4] += blo(v0.z); a0[5] += bhi(v0.z); a0[6] += blo(v0.w); a0[7] += bhi(v0.w);
        }
    }
    float dt = rsqrtf((float)(end - beg) + 1.f);
    float4 o0, o1;
    o0.x = (a0[0] + a1[0] + a2[0] + a3[0]) * dt;
    o0.y = (a0[1] + a1[1] + a2[1] + a3[1]) * dt;
    o0.z = (a0[2] + a1[2] + a2[2] + a3[2]) * dt;
    o0.w = (a0[3] + a1[3] + a2[3] + a3[3]) * dt;
    o1.x = (a0[4] + a1[4] + a2[4] + a3[4]) * dt;
    o1.y = (a0[5] + a1[5] + a2[5] + a3[5]) * dt;
    o1.z = (a0[6] + a1[6] + a2[6] + a3[6]) * dt;
    o1.w = (a0[7] + a1[7] + a2[7] + a3[7]) * dt;
    float4* out = (float4*)(agg + (size_t)node * C + l * 8);
    out[0] = o0; out[1] = o1;
}

// ---- per-channel sum / sumsq over nodes ----
__global__ void __launch_bounds__(256) k_stats(const float* __restrict__ agg,
                                               float* __restrict__ sums,
                                               float* __restrict__ sumsq) {
    int tx = threadIdx.x;
    int r = blockIdx.x * 8 + threadIdx.y;
    int stride = gridDim.x * 8;
    const float4* a4 = (const float4*)agg;
    float4 s = {0,0,0,0}, q = {0,0,0,0};
    for (; r < N_NODES; r += stride) {
        float4 v = a4[(size_t)r * 32 + tx];
        s.x += v.x; s.y += v.y; s.z += v.z; s.w += v.w;
        q.x += v.x * v.x; q.y += v.y * v.y; q.z += v.z * v.z; q.w += v.w * v.w;
    }
    __shared__ float4 ls[8][32], lq[8][32];
    ls[threadIdx.y][tx] = s; lq[threadIdx.y][tx] = q;
    __syncthreads();
    if (threadIdx.y == 0) {
        for (int w = 1; w < 8; ++w) {
            float4 v = ls[w][tx], u = lq[w][tx];
            s.x += v.x; s.y += v.y; s.z += v.z; s.w += v.w;
            q.x += u.x; q.y += u.y; q.z += u.z; q.w += u.w;
        }
        int c = tx * 4;
        atomicAdd(&sums[c + 0], s.x); atomicAdd(&sums[c + 1], s.y);
        atomicAdd(&sums[c + 2], s.z); atomicAdd(&sums[c + 3], s.w);
        atomicAdd(&sumsq[c + 0], q.x); atomicAdd(&sumsq[c + 1], q.y);
        atomicAdd(&sumsq[c + 2], q.z); atomicAdd(&sumsq[c + 3], q.w);
    }
}

// ---- y = relu(agg*scale + shift); bias cancels in BN ----
__global__ void __launch_bounds__(256) k_final(float* __restrict__ agg,
                                               const float* __restrict__ sums,
                                               const float* __restrict__ sumsq,
                                               const float* __restrict__ gamma,
                                               const float* __restrict__ beta) {
    __shared__ float sc_s[C], sh_s[C];
    int tid = threadIdx.x;
    if (tid < C) {
        float mean = sums[tid] * (1.0f / N_NODES);
        float var = sumsq[tid] * (1.0f / N_NODES) - mean * mean;
        float sc = gamma[tid] * rsqrtf(var + BN_EPS);
        sc_s[tid] = sc;
        sh_s[tid] = beta[tid] - mean * sc;
    }
    __syncthreads();
    int i = blockIdx.x * 256 + tid;
    if (i >= N_NODES * 32) return;
    int c = (i & 31) * 4;
    float4 v = ((float4*)agg)[i];
    v.x = fmaxf(v.x * sc_s[c + 0] + sh_s[c + 0], 0.f);
    v.y = fmaxf(v.y * sc_s[c + 1] + sh_s[c + 1], 0.f);
    v.z = fmaxf(v.z * sc_s[c + 2] + sh_s[c + 2], 0.f);
    v.w = fmaxf(v.w * sc_s[c + 3] + sh_s[c + 3], 0.f);
    ((float4*)agg)[i] = v;
}

extern "C" void kernel_launch(void* const* d_in, const int* in_sizes, int n_in,
                              void* d_out, int out_size, void* d_ws, size_t ws_size,
                              hipStream_t stream) {
    const float* x     = (const float*)d_in[0];
    const float* W     = (const float*)d_in[1];
    // d_in[2] = bias: cancels in BatchNorm, unused
    const float* gamma = (const float*)d_in[3];
    const float* beta  = (const float*)d_in[4];
    const int*   eidx  = (const int*)d_in[5];
    const int* row = eidx;
    const int* col = eidx + N_EDGES;

    float* agg = (float*)d_out;  // [N, C], finalized in place

    // workspace layout
    unsigned* g = (unsigned*)d_ws;                               // [N*64] bf16x2 rows (12.8 MB)
    unsigned short* srcs = (unsigned short*)(g + (size_t)N_NODES * 64); // [E] u16 (1.6 MB)
    int*   cnt    = (int*)(srcs + N_EDGES);                      // [N]
    int*   offs   = cnt + N_NODES;                               // [N+1]
    int*   bcur   = offs + N_NODES + 1;                          // [NBUCK]  -- zeroed
    float* sums   = (float*)(bcur + NBUCK);                      // [C]      -- zeroed
    float* sumsq  = sums + C;                                    // [C]      -- zeroed
    unsigned* WTn = (unsigned*)(sumsq + C);                      // [8192] bf16x2 (W, MFMA-B layout)
    unsigned* bEdges = WTn + 8192;                               // [NBUCK*SLOT] (6.4 MB)

    hipMemsetAsync(bcur, 0, (size_t)(NBUCK + 2 * C) * sizeof(int), stream);
    k_scat<<<A_BLOCKS, 256, 0, stream>>>(row, col, bcur, bEdges, W, WTn);
    k_bsort<<<NBUCK, 256, 0, stream>>>(bEdges, bcur, offs, cnt, srcs);
    k_gemm<<<(N_NODES + 63) / 64, 256, 0, stream>>>(x, WTn, cnt, (unsigned short*)g);
    k_gather<<<(N_NODES + 15) / 16, 256, 0, stream>>>(offs, srcs, (const uint4*)g, agg);
    k_stats<<<256, dim3(32, 8), 0, stream>>>(agg, sums, sumsq);
    k_final<<<(N_NODES * 32 + 255) / 256, 256, 0, stream>>>(agg, sums, sumsq, gamma, beta);
}

// Round 3
// 194.835 us; speedup vs baseline: 1.3113x; 1.0383x over previous
//
#include <hip/hip_runtime.h>

#define N_NODES 50000
#define N_EDGES 800000
#define C 128
#define BN_EPS 1e-5f
#define BSHIFT 7                              // 128 nodes per bucket
#define NBUCK ((N_NODES + 127) >> BSHIFT)     // 391
#define EPB 2048                              // edges per scat block
#define A_BLOCKS ((N_EDGES + EPB - 1) / EPB)  // 391
#define EBUF 2560                             // per-bucket staging cap (mean 2048, +11 sigma)

typedef __attribute__((ext_vector_type(8))) short bf16x8;
typedef __attribute__((ext_vector_type(4))) float f32x4;

__device__ __forceinline__ unsigned pack_bf16x2(float a, float b) {
    unsigned ua = __float_as_uint(a);
    ua = (ua + 0x7FFFu + ((ua >> 16) & 1u)) >> 16;   // RNE
    unsigned ub = __float_as_uint(b);
    ub = (ub + 0x7FFFu + ((ub >> 16) & 1u)) >> 16;
    return ua | (ub << 16);
}

__device__ __forceinline__ unsigned short bf16_1(float a) {
    unsigned u = __float_as_uint(a);
    return (unsigned short)((u + 0x7FFFu + ((u >> 16) & 1u)) >> 16);
}

__device__ __forceinline__ float blo(unsigned u) { return __uint_as_float(u << 16); }
__device__ __forceinline__ float bhi(unsigned u) { return __uint_as_float(u & 0xFFFF0000u); }

__device__ __forceinline__ unsigned pack_f16x2(float a, float b) {
    _Float16 ha = (_Float16)a, hb = (_Float16)b;
    return (unsigned)__builtin_bit_cast(unsigned short, ha) |
           ((unsigned)__builtin_bit_cast(unsigned short, hb) << 16);
}
__device__ __forceinline__ float f16lo(unsigned u) {
    return (float)__builtin_bit_cast(_Float16, (unsigned short)(u & 0xFFFFu));
}
__device__ __forceinline__ float f16hi(unsigned u) {
    return (float)__builtin_bit_cast(_Float16, (unsigned short)(u >> 16));
}

// ---- pass 1: per-block counting sort of 2048 edges into OWN bEdges region,
//      grouped by bucket; scanned per-bucket offsets -> bOffsT[b][w].
//      NO device atomics. Block 0 also builds the MFMA-B-layout bf16 W.
// WTn layout (dword index i = ((nt*4+kt)*64 + q*16+m)*4 + j):
//   pack( W[kt*32+q*8+2j][nt*16+m], W[kt*32+q*8+2j+1][nt*16+m] )
__global__ void __launch_bounds__(256) k_scat(const int* __restrict__ row,
                                              const int* __restrict__ col,
                                              unsigned* __restrict__ bEdges,
                                              int* __restrict__ bOffsT,
                                              const float* __restrict__ W,
                                              unsigned* __restrict__ WTn) {
    __shared__ int hist[NBUCK];
    __shared__ int pbuf[2][512];
    int tid = threadIdx.x, w = blockIdx.x;
    for (int i = tid; i < NBUCK; i += 256) hist[i] = 0;
    __syncthreads();
    int e0 = w * EPB;
    int nE = N_EDGES - e0; if (nE > EPB) nE = EPB;
    int myc[8], myr[8];
#pragma unroll
    for (int k = 0; k < 8; ++k) {
        int idx = tid + (k << 8);
        bool ok = idx < nE;
        myc[k] = ok ? col[e0 + idx] : -1;
        myr[k] = ok ? row[e0 + idx] : 0;
        if (ok) atomicAdd(&hist[myc[k] >> BSHIFT], 1);
    }
    if (w == 0) {  // build W while hist atomics drain
#pragma unroll
        for (int it = 0; it < 32; ++it) {
            int i = tid + (it << 8);
            int j = i & 3, l = (i >> 2) & 63, kt = (i >> 8) & 3, nt = i >> 10;
            int m = l & 15, q = l >> 4;
            int kr = kt * 32 + q * 8 + 2 * j;
            int n = nt * 16 + m;
            WTn[i] = pack_bf16x2(W[kr * C + n], W[(kr + 1) * C + n]);
        }
    }
    __syncthreads();
    // inclusive scan of hist (512-padded Hillis-Steele, double-buffered)
    for (int i = tid; i < 512; i += 256) pbuf[0][i] = (i < NBUCK) ? hist[i] : 0;
    __syncthreads();
    int src = 0;
    for (int d = 1; d < 512; d <<= 1) {
        for (int i = tid; i < 512; i += 256) {
            int v = pbuf[src][i];
            if (i >= d) v += pbuf[src][i - d];
            pbuf[src ^ 1][i] = v;
        }
        src ^= 1;
        __syncthreads();
    }
    // write exclusive offsets column w (rows 0..NBUCK), reset hist to cursors
    for (int b = tid; b <= NBUCK; b += 256)
        bOffsT[b * A_BLOCKS + w] = b ? pbuf[src][b - 1] : 0;
    for (int b = tid; b < NBUCK; b += 256)
        hist[b] = b ? pbuf[src][b - 1] : 0;
    __syncthreads();
#pragma unroll
    for (int k = 0; k < 8; ++k) {
        if (myc[k] >= 0) {
            int b = myc[k] >> BSHIFT;
            int r = atomicAdd(&hist[b], 1);  // LDS only
            bEdges[(size_t)w * EPB + r] = (unsigned)myr[k] | ((unsigned)myc[k] << 16);
        }
    }
}

// ---- pass 2: bucket block b assembles its edges from 391 regions (offsets
//      known arithmetically), node histogram + scan -> offs/cnt, scatter srcs ----
__global__ void __launch_bounds__(256) k_bsort(const unsigned* __restrict__ bEdges,
                                               const int* __restrict__ bOffsT,
                                               int* __restrict__ offs,
                                               int* __restrict__ cnt,
                                               unsigned short* __restrict__ srcs) {
    __shared__ int sS[A_BLOCKS];
    __shared__ int sO[A_BLOCKS + 1];
    __shared__ int pbuf[2][512];
    __shared__ int red[256];
    __shared__ unsigned ebuf[EBUF];
    __shared__ int h[128];
    __shared__ int wtot;
    int tid = threadIdx.x, b = blockIdx.x;
    // load row b (starts) and row b+1; counts = diff
    for (int i = tid; i < A_BLOCKS; i += 256) {
        int s = bOffsT[b * A_BLOCKS + i];
        int e = bOffsT[(b + 1) * A_BLOCKS + i];
        sS[i] = s;
        pbuf[0][i] = e - s;
    }
    for (int i = tid; i < 512; i += 256) if (i >= A_BLOCKS) pbuf[0][i] = 0;
    if (tid < 128) h[tid] = 0;
    __syncthreads();
    // e0 = sum of starts (tree reduce)
    red[tid] = ((tid < A_BLOCKS) ? sS[tid] : 0) + ((tid + 256 < A_BLOCKS) ? sS[tid + 256] : 0);
    // inclusive scan of counts
    int src = 0;
    for (int d = 1; d < 512; d <<= 1) {
        for (int i = tid; i < 512; i += 256) {
            int v = pbuf[src][i];
            if (i >= d) v += pbuf[src][i - d];
            pbuf[src ^ 1][i] = v;
        }
        src ^= 1;
        __syncthreads();
    }
#pragma unroll
    for (int s = 128; s > 0; s >>= 1) {
        if (tid < s) red[tid] += red[tid + s];
        __syncthreads();
    }
    int e0 = red[0];
    for (int i = tid; i <= A_BLOCKS; i += 256)
        sO[i] = i ? pbuf[src][i - 1] : 0;
    __syncthreads();
    int c = sO[A_BLOCKS];
    if (c > EBUF) c = EBUF;  // statistically impossible; memory-safety only
    // stage: flat index, binary-search segment, coalesced global reads
    for (int e = tid; e < c; e += 256) {
        int lo = 0, hi = A_BLOCKS;
        while (hi - lo > 1) {
            int mid = (lo + hi) >> 1;
            if (sO[mid] <= e) lo = mid; else hi = mid;
        }
        ebuf[e] = bEdges[(size_t)lo * EPB + sS[lo] + (e - sO[lo])];
    }
    __syncthreads();
    int n0 = b << BSHIFT;
    int nn = N_NODES - n0; if (nn > 128) nn = 128;
    for (int e = tid; e < c; e += 256)
        atomicAdd(&h[(int)(ebuf[e] >> 16) - n0], 1);
    __syncthreads();
    int v = 0, sc = 0;
    if (tid < 128) {
        int lane = tid & 63;
        v = h[tid];
        sc = v;
#pragma unroll
        for (int d = 1; d < 64; d <<= 1) {
            int u = __shfl_up(sc, d, 64);
            if (lane >= d) sc += u;
        }
        if (tid == 63) wtot = sc;
    }
    __syncthreads();
    if (tid < 128) {
        int ex = sc - v + ((tid >= 64) ? wtot : 0);
        if (tid < nn) { offs[n0 + tid] = e0 + ex; cnt[n0 + tid] = v; }
        h[tid] = ex;  // reuse as cursor
    }
    __syncthreads();
    for (int e = tid; e < c; e += 256) {
        unsigned pe = ebuf[e];
        int r = atomicAdd(&h[(int)(pe >> 16) - n0], 1);
        srcs[e0 + r] = (unsigned short)(pe & 0xFFFFu);
    }
    if (b == NBUCK - 1 && tid == 0) offs[N_NODES] = N_EDGES;
}

// ---- g(bf16) = dinv[row]*(x@W) via MFMA 16x16x32 bf16; coalesced B loads.
//      Block 0 zeroes the BN accumulators (runs well before k_stats). ----
__global__ void __launch_bounds__(256) k_gemm(const float* __restrict__ x,
                                              const unsigned* __restrict__ WTn,
                                              const int* __restrict__ cnt,
                                              unsigned short* __restrict__ g,
                                              float* __restrict__ sums) {
    __shared__ unsigned xs[64 * 68];  // 64 rows x 68 dwords (128 bf16 + pad)
    int tid = threadIdx.x;
    if (blockIdx.x == 0) sums[tid] = 0.f;  // sums[128]+sumsq[128] contiguous
    int r0 = blockIdx.x * 64;
    const float4* x4 = (const float4*)x;
#pragma unroll
    for (int it = 0; it < 8; ++it) {
        int i = tid + (it << 8);
        int row = i >> 5, c4 = i & 31;
        float4 v = {0.f, 0.f, 0.f, 0.f};
        if (r0 + row < N_NODES) v = x4[(size_t)(r0 + row) * 32 + c4];
        xs[row * 68 + c4 * 2]     = pack_bf16x2(v.x, v.y);
        xs[row * 68 + c4 * 2 + 1] = pack_bf16x2(v.z, v.w);
    }
    __syncthreads();
    int wave = tid >> 6, lane = tid & 63;
    int r0w = r0 + wave * 16;
    if (r0w >= N_NODES) return;
    int m = lane & 15, q = lane >> 4;
    bf16x8 afrag[4];
#pragma unroll
    for (int kt = 0; kt < 4; ++kt)
        afrag[kt] = *(const bf16x8*)&xs[(wave * 16 + m) * 68 + kt * 16 + q * 4];
    const uint4* B4 = (const uint4*)WTn;
    f32x4 acc[8];
#pragma unroll
    for (int nt = 0; nt < 8; ++nt)
        acc[nt][0] = acc[nt][1] = acc[nt][2] = acc[nt][3] = 0.f;
#pragma unroll
    for (int nt = 0; nt < 8; ++nt) {
#pragma unroll
        for (int kt = 0; kt < 4; ++kt) {
            uint4 braw = B4[(nt * 4 + kt) * 64 + lane];   // coalesced 1 KB/instr
            bf16x8 bfrag = __builtin_bit_cast(bf16x8, braw);
            acc[nt] = __builtin_amdgcn_mfma_f32_16x16x32_bf16(afrag[kt], bfrag, acc[nt], 0, 0, 0);
        }
    }
    int rb = r0w + q * 4;
    float dv[4];
#pragma unroll
    for (int reg = 0; reg < 4; ++reg) dv[reg] = rsqrtf((float)cnt[rb + reg] + 1.f);
#pragma unroll
    for (int nt = 0; nt < 8; ++nt) {
        int cbase = nt * 16 + m;
#pragma unroll
        for (int reg = 0; reg < 4; ++reg)
            g[(size_t)(rb + reg) * C + cbase] = bf16_1(acc[nt][reg] * dv[reg]);
    }
}

// ---- gather: one wave per node; 16 channel-lanes x 4 source-slots;
//      xor-reduce over slots; f16 output row (128 ch = 64 u32) ----
#define ACC8(v) { a[0]+=blo(v.x); a[1]+=bhi(v.x); a[2]+=blo(v.y); a[3]+=bhi(v.y); \
                  a[4]+=blo(v.z); a[5]+=bhi(v.z); a[6]+=blo(v.w); a[7]+=bhi(v.w); }
__global__ void __launch_bounds__(256) k_gather(const int* __restrict__ offs,
                                                const unsigned short* __restrict__ srcs,
                                                const uint4* __restrict__ g4,
                                                unsigned* __restrict__ aggh) {
    int tid = threadIdx.x;
    int node = blockIdx.x * 4 + (tid >> 6);   // grid exactly N/4
    int lane = tid & 63, l = lane & 15, q = lane >> 4;
    int beg = offs[node], end = offs[node + 1];
    float a[8];
    if (q == 0) {
        uint4 u = g4[(size_t)node * 16 + l];  // self-loop term
        a[0]=blo(u.x); a[1]=bhi(u.x); a[2]=blo(u.y); a[3]=bhi(u.y);
        a[4]=blo(u.z); a[5]=bhi(u.z); a[6]=blo(u.w); a[7]=bhi(u.w);
    } else {
#pragma unroll
        for (int i = 0; i < 8; ++i) a[i] = 0.f;
    }
    for (int base = beg; base < end; base += 64) {
        int nb = end - base; if (nb > 64) nb = 64;
        int sv = (base + lane < end) ? (int)srcs[base + lane] : 0;
        int j0 = 0;
        for (; j0 + 16 <= nb; j0 += 16) {  // full groups: 4 loads in flight/lane
            int i0 = j0 + q;
            int s0 = __shfl(sv, i0, 64);
            int s1 = __shfl(sv, i0 + 4, 64);
            int s2 = __shfl(sv, i0 + 8, 64);
            int s3 = __shfl(sv, i0 + 12, 64);
            uint4 v0 = g4[(size_t)s0 * 16 + l];
            uint4 v1 = g4[(size_t)s1 * 16 + l];
            uint4 v2 = g4[(size_t)s2 * 16 + l];
            uint4 v3 = g4[(size_t)s3 * 16 + l];
            ACC8(v0) ACC8(v1) ACC8(v2) ACC8(v3)
        }
        if (j0 < nb) {  // tail group
#pragma unroll
            for (int k = 0; k < 4; ++k) {
                int idx = j0 + q + 4 * k;
                int s = __shfl(sv, idx, 64);
                if (idx < nb) { uint4 v = g4[(size_t)s * 16 + l]; ACC8(v) }
            }
        }
    }
#pragma unroll
    for (int i = 0; i < 8; ++i) {
        a[i] += __shfl_xor(a[i], 16, 64);
        a[i] += __shfl_xor(a[i], 32, 64);
    }
    float dt = rsqrtf((float)(end - beg) + 1.f);
    if (q < 2) {
        unsigned p0 = pack_f16x2(a[q * 4 + 0] * dt, a[q * 4 + 1] * dt);
        unsigned p1 = pack_f16x2(a[q * 4 + 2] * dt, a[q * 4 + 3] * dt);
        uint2 pv; pv.x = p0; pv.y = p1;
        *(uint2*)(aggh + (size_t)node * 64 + l * 4 + q * 2) = pv;
    }
}

// ---- per-channel sum / sumsq over f16 agg rows ----
__global__ void __launch_bounds__(256) k_stats(const unsigned* __restrict__ aggh,
                                               float* __restrict__ sums,
                                               float* __restrict__ sumsq) {
    int tid = threadIdx.x;
    int tx = tid & 15, ty = tid >> 4;
    int r = blockIdx.x * 16 + ty, stride = gridDim.x * 16;
    const uint4* a4 = (const uint4*)aggh;
    float s[8] = {0,0,0,0,0,0,0,0}, qq[8] = {0,0,0,0,0,0,0,0};
    for (; r < N_NODES; r += stride) {
        uint4 v = a4[(size_t)r * 16 + tx];
        float f0=f16lo(v.x), f1=f16hi(v.x), f2=f16lo(v.y), f3=f16hi(v.y);
        float f4=f16lo(v.z), f5=f16hi(v.z), f6=f16lo(v.w), f7=f16hi(v.w);
        s[0]+=f0; s[1]+=f1; s[2]+=f2; s[3]+=f3; s[4]+=f4; s[5]+=f5; s[6]+=f6; s[7]+=f7;
        qq[0]+=f0*f0; qq[1]+=f1*f1; qq[2]+=f2*f2; qq[3]+=f3*f3;
        qq[4]+=f4*f4; qq[5]+=f5*f5; qq[6]+=f6*f6; qq[7]+=f7*f7;
    }
    __shared__ float ls[256][8], lq[256][8];
#pragma unroll
    for (int i = 0; i < 8; ++i) { ls[tid][i] = s[i]; lq[tid][i] = qq[i]; }
    __syncthreads();
    if (tid < 16) {
        for (int y = 1; y < 16; ++y)
#pragma unroll
            for (int i = 0; i < 8; ++i) { s[i] += ls[tid + y * 16][i]; qq[i] += lq[tid + y * 16][i]; }
#pragma unroll
        for (int i = 0; i < 8; ++i) {
            atomicAdd(&sums[tid * 8 + i], s[i]);
            atomicAdd(&sumsq[tid * 8 + i], qq[i]);
        }
    }
}

// ---- y = relu(aggh*scale + shift) -> f32 out; bias cancels in BN ----
__global__ void __launch_bounds__(256) k_final(const unsigned* __restrict__ aggh,
                                               float* __restrict__ out,
                                               const float* __restrict__ sums,
                                               const float* __restrict__ sumsq,
                                               const float* __restrict__ gamma,
                                               const float* __restrict__ beta) {
    __shared__ float sc_s[C], sh_s[C];
    int tid = threadIdx.x;
    if (tid < C) {
        float mean = sums[tid] * (1.0f / N_NODES);
        float var = sumsq[tid] * (1.0f / N_NODES) - mean * mean;
        float sc = gamma[tid] * rsqrtf(var + BN_EPS);
        sc_s[tid] = sc;
        sh_s[tid] = beta[tid] - mean * sc;
    }
    __syncthreads();
    int i = blockIdx.x * 256 + tid;          // uint4 index over aggh, N*16 total
    uint4 v = ((const uint4*)aggh)[i];
    int c = (i & 15) * 8;
    float4 o0, o1;
    o0.x = fmaxf(f16lo(v.x) * sc_s[c+0] + sh_s[c+0], 0.f);
    o0.y = fmaxf(f16hi(v.x) * sc_s[c+1] + sh_s[c+1], 0.f);
    o0.z = fmaxf(f16lo(v.y) * sc_s[c+2] + sh_s[c+2], 0.f);
    o0.w = fmaxf(f16hi(v.y) * sc_s[c+3] + sh_s[c+3], 0.f);
    o1.x = fmaxf(f16lo(v.z) * sc_s[c+4] + sh_s[c+4], 0.f);
    o1.y = fmaxf(f16hi(v.z) * sc_s[c+5] + sh_s[c+5], 0.f);
    o1.z = fmaxf(f16lo(v.w) * sc_s[c+6] + sh_s[c+6], 0.f);
    o1.w = fmaxf(f16hi(v.w) * sc_s[c+7] + sh_s[c+7], 0.f);
    float4* o = (float4*)(out + (size_t)i * 8);
    o[0] = o0; o[1] = o1;
}

extern "C" void kernel_launch(void* const* d_in, const int* in_sizes, int n_in,
                              void* d_out, int out_size, void* d_ws, size_t ws_size,
                              hipStream_t stream) {
    const float* x     = (const float*)d_in[0];
    const float* W     = (const float*)d_in[1];
    // d_in[2] = bias: cancels in BatchNorm, unused
    const float* gamma = (const float*)d_in[3];
    const float* beta  = (const float*)d_in[4];
    const int*   eidx  = (const int*)d_in[5];
    const int* row = eidx;
    const int* col = eidx + N_EDGES;

    float* out = (float*)d_out;  // [N, C] f32

    // workspace layout (all 16B-aligned)
    unsigned* g      = (unsigned*)d_ws;                          // [N*64] bf16x2 rows (12.8 MB)
    unsigned* aggh   = g + (size_t)N_NODES * 64;                 // [N*64] f16x2 rows (12.8 MB)
    unsigned* bEdges = aggh + (size_t)N_NODES * 64;              // [A_BLOCKS*EPB] (3.2 MB)
    unsigned* WTn    = bEdges + (size_t)A_BLOCKS * EPB;          // [8192] bf16x2 (W, MFMA-B layout)
    unsigned short* srcs = (unsigned short*)(WTn + 8192);        // [E] u16 (1.6 MB)
    int*   cnt    = (int*)(srcs + N_EDGES);                      // [N]
    int*   offs   = cnt + N_NODES;                               // [N+1] (+3 pad)
    float* sums   = (float*)(offs + N_NODES + 4);                // [C]  (zeroed by k_gemm b0)
    float* sumsq  = sums + C;                                    // [C]
    int*   bOffsT = (int*)(sumsq + C);                           // [(NBUCK+1)*A_BLOCKS] (613 KB)

    k_scat<<<A_BLOCKS, 256, 0, stream>>>(row, col, bEdges, bOffsT, W, WTn);
    k_bsort<<<NBUCK, 256, 0, stream>>>(bEdges, bOffsT, offs, cnt, srcs);
    k_gemm<<<(N_NODES + 63) / 64, 256, 0, stream>>>(x, WTn, cnt, (unsigned short*)g, sums);
    k_gather<<<N_NODES / 4, 256, 0, stream>>>(offs, srcs, (const uint4*)g, aggh);
    k_stats<<<128, 256, 0, stream>>>(aggh, sums, sumsq);
    k_final<<<N_NODES * 16 / 256, 256, 0, stream>>>(aggh, out, sums, sumsq, gamma, beta);
}

// Round 4
// 162.517 us; speedup vs baseline: 1.5720x; 1.1989x over previous
//
#include <hip/hip_runtime.h>

#define N_NODES 50000
#define N_EDGES 800000
#define C 128
#define BN_EPS 1e-5f
#define BSHIFT 7                              // 128 nodes per bucket
#define NBUCK ((N_NODES + 127) >> BSHIFT)     // 391
#define EPB 2048                              // edges per scat block
#define A_BLOCKS ((N_EDGES + EPB - 1) / EPB)  // 391
#define EBUF 2560                             // per-bucket staging cap (mean 2046, +11 sigma)
#define GATHER_BLOCKS 512
#define GATHER_WAVES (GATHER_BLOCKS * 8)      // 4096

typedef __attribute__((ext_vector_type(8))) short bf16x8;
typedef __attribute__((ext_vector_type(4))) float f32x4;

__device__ __forceinline__ unsigned pack_bf16x2(float a, float b) {
    unsigned ua = __float_as_uint(a);
    ua = (ua + 0x7FFFu + ((ua >> 16) & 1u)) >> 16;   // RNE
    unsigned ub = __float_as_uint(b);
    ub = (ub + 0x7FFFu + ((ub >> 16) & 1u)) >> 16;
    return ua | (ub << 16);
}

__device__ __forceinline__ unsigned short bf16_1(float a) {
    unsigned u = __float_as_uint(a);
    return (unsigned short)((u + 0x7FFFu + ((u >> 16) & 1u)) >> 16);
}

__device__ __forceinline__ float blo(unsigned u) { return __uint_as_float(u << 16); }
__device__ __forceinline__ float bhi(unsigned u) { return __uint_as_float(u & 0xFFFF0000u); }

__device__ __forceinline__ unsigned pack_f16x2(float a, float b) {
    _Float16 ha = (_Float16)a, hb = (_Float16)b;
    return (unsigned)__builtin_bit_cast(unsigned short, ha) |
           ((unsigned)__builtin_bit_cast(unsigned short, hb) << 16);
}
__device__ __forceinline__ float f16lo(unsigned u) {
    return (float)__builtin_bit_cast(_Float16, (unsigned short)(u & 0xFFFFu));
}
__device__ __forceinline__ float f16hi(unsigned u) {
    return (float)__builtin_bit_cast(_Float16, (unsigned short)(u >> 16));
}

// ---- pass 1: per-block counting sort of 2048 edges into OWN bEdges region,
//      grouped by bucket; exclusive per-bucket offsets -> bOffsT[b][w].
//      Register shfl-scan (2 vals/thread). No device atomics.
//      Block 0 also builds the MFMA-B-layout bf16 W.
__global__ void __launch_bounds__(256) k_scat(const int* __restrict__ row,
                                              const int* __restrict__ col,
                                              unsigned* __restrict__ bEdges,
                                              int* __restrict__ bOffsT,
                                              const float* __restrict__ W,
                                              unsigned* __restrict__ WTn) {
    __shared__ int hist[NBUCK];
    __shared__ int wsum[8];
    int tid = threadIdx.x, w = blockIdx.x;
    int lane = tid & 63, wid = tid >> 6;
    for (int i = tid; i < NBUCK; i += 256) hist[i] = 0;
    __syncthreads();
    int e0 = w * EPB;
    int nE = N_EDGES - e0; if (nE > EPB) nE = EPB;
    int myc[8], myr[8];
#pragma unroll
    for (int k = 0; k < 8; ++k) {
        int idx = tid + (k << 8);
        bool ok = idx < nE;
        myc[k] = ok ? col[e0 + idx] : -1;
        myr[k] = ok ? row[e0 + idx] : 0;
        if (ok) atomicAdd(&hist[myc[k] >> BSHIFT], 1);
    }
    if (w == 0) {  // build W while hist atomics drain
#pragma unroll
        for (int it = 0; it < 32; ++it) {
            int i = tid + (it << 8);
            int j = i & 3, l = (i >> 2) & 63, kt = (i >> 8) & 3, nt = i >> 10;
            int m = l & 15, q = l >> 4;
            int kr = kt * 32 + q * 8 + 2 * j;
            int n = nt * 16 + m;
            WTn[i] = pack_bf16x2(W[kr * C + n], W[(kr + 1) * C + n]);
        }
    }
    __syncthreads();
    // register scan over 391 buckets: positions tid and tid+256
    int v0 = hist[tid];
    int v1 = (tid + 256 < NBUCK) ? hist[tid + 256] : 0;
    int s0 = v0, s1 = v1;
#pragma unroll
    for (int d = 1; d < 64; d <<= 1) {
        int u0 = __shfl_up(s0, d, 64);
        int u1 = __shfl_up(s1, d, 64);
        if (lane >= d) { s0 += u0; s1 += u1; }
    }
    if (lane == 63) { wsum[wid] = s0; wsum[4 + wid] = s1; }
    __syncthreads();
    int tot0 = wsum[0] + wsum[1] + wsum[2] + wsum[3];
    int p0 = 0, p1 = tot0;
    for (int i = 0; i < wid; ++i) { p0 += wsum[i]; p1 += wsum[4 + i]; }
    int exc0 = p0 + s0 - v0;
    int exc1 = p1 + s1 - v1;
    bOffsT[tid * A_BLOCKS + w] = exc0;
    if (tid + 256 < NBUCK) bOffsT[(tid + 256) * A_BLOCKS + w] = exc1;
    if (tid == 0) bOffsT[NBUCK * A_BLOCKS + w] = nE;
    hist[tid] = exc0;                                   // cursors
    if (tid + 256 < NBUCK) hist[tid + 256] = exc1;
    __syncthreads();
#pragma unroll
    for (int k = 0; k < 8; ++k) {
        if (myc[k] >= 0) {
            int b = myc[k] >> BSHIFT;
            int r = atomicAdd(&hist[b], 1);  // LDS only
            bEdges[(size_t)w * EPB + r] = (unsigned)myr[k] | ((unsigned)myc[k] << 16);
        }
    }
}

// ---- pass 2: bucket block b assembles its edges from 391 regions; segment-
//      per-thread staging (no search); node histogram + scan -> offs/cnt/srcs ----
__global__ void __launch_bounds__(256) k_bsort(const unsigned* __restrict__ bEdges,
                                               const int* __restrict__ bOffsT,
                                               int* __restrict__ offs,
                                               int* __restrict__ cnt,
                                               unsigned short* __restrict__ srcs) {
    __shared__ int sS[A_BLOCKS];
    __shared__ int sO[A_BLOCKS + 1];
    __shared__ unsigned ebuf[EBUF];
    __shared__ int h[128];
    __shared__ int wsum[12];
    __shared__ int wtot;
    int tid = threadIdx.x, b = blockIdx.x;
    int lane = tid & 63, wid = tid >> 6;
    int i1 = tid + 256;
    int st0 = bOffsT[b * A_BLOCKS + tid];
    int v0 = bOffsT[(b + 1) * A_BLOCKS + tid] - st0;
    int st1 = 0, v1 = 0;
    if (i1 < A_BLOCKS) {
        st1 = bOffsT[b * A_BLOCKS + i1];
        v1 = bOffsT[(b + 1) * A_BLOCKS + i1] - st1;
    }
    sS[tid] = st0;
    if (i1 < A_BLOCKS) sS[i1] = st1;
    if (tid < 128) h[tid] = 0;
    // e0 = sum of starts; scan of counts -> sO (register shfl versions)
    int ep = st0 + st1;
    int s0 = v0, s1 = v1;
#pragma unroll
    for (int d = 1; d < 64; d <<= 1) {
        int u0 = __shfl_up(s0, d, 64);
        int u1 = __shfl_up(s1, d, 64);
        if (lane >= d) { s0 += u0; s1 += u1; }
        ep += __shfl_xor(ep, d, 64);
    }
    if (lane == 63) { wsum[wid] = s0; wsum[4 + wid] = s1; }
    if (lane == 0) wsum[8 + wid] = ep;
    __syncthreads();
    int tot0 = wsum[0] + wsum[1] + wsum[2] + wsum[3];
    int tot1 = wsum[4] + wsum[5] + wsum[6] + wsum[7];
    int e0 = wsum[8] + wsum[9] + wsum[10] + wsum[11];
    int p0 = 0, p1 = tot0;
    for (int i = 0; i < wid; ++i) { p0 += wsum[i]; p1 += wsum[4 + i]; }
    sO[tid] = p0 + s0 - v0;
    if (i1 < A_BLOCKS) sO[i1] = p1 + s1 - v1;
    if (tid == 0) sO[A_BLOCKS] = tot0 + tot1;
    __syncthreads();
    int c = sO[A_BLOCKS];
    if (c > EBUF) c = EBUF;  // statistically impossible; memory-safety only
    // stage: each thread copies its segments sequentially (offsets known)
    for (int seg = tid; seg < A_BLOCKS; seg += 256) {
        int o = sO[seg];
        int n = sO[seg + 1] - o;
        const unsigned* srcp = bEdges + (size_t)seg * EPB + sS[seg];
        for (int k = 0; k < n; ++k) {
            int dp = o + k;
            if (dp < EBUF) ebuf[dp] = srcp[k];
        }
    }
    __syncthreads();
    int n0 = b << BSHIFT;
    int nn = N_NODES - n0; if (nn > 128) nn = 128;
    for (int e = tid; e < c; e += 256)
        atomicAdd(&h[(int)(ebuf[e] >> 16) - n0], 1);
    __syncthreads();
    int v = 0, sc = 0;
    if (tid < 128) {
        int ln = tid & 63;
        v = h[tid];
        sc = v;
#pragma unroll
        for (int d = 1; d < 64; d <<= 1) {
            int u = __shfl_up(sc, d, 64);
            if (ln >= d) sc += u;
        }
        if (tid == 63) wtot = sc;
    }
    __syncthreads();
    if (tid < 128) {
        int ex = sc - v + ((tid >= 64) ? wtot : 0);
        if (tid < nn) { offs[n0 + tid] = e0 + ex; cnt[n0 + tid] = v; }
        h[tid] = ex;  // reuse as cursor
    }
    __syncthreads();
    for (int e = tid; e < c; e += 256) {
        unsigned pe = ebuf[e];
        int r = atomicAdd(&h[(int)(pe >> 16) - n0], 1);
        srcs[e0 + r] = (unsigned short)(pe & 0xFFFFu);
    }
    if (b == NBUCK - 1 && tid == 0) offs[N_NODES] = N_EDGES;
}

// ---- g(bf16) = dinv[row]*(x@W) via MFMA 16x16x32 bf16; coalesced B loads.
//      Block 0 zeroes the 8-sliced BN accumulators. ----
__global__ void __launch_bounds__(256) k_gemm(const float* __restrict__ x,
                                              const unsigned* __restrict__ WTn,
                                              const int* __restrict__ cnt,
                                              unsigned short* __restrict__ g,
                                              float* __restrict__ sums8) {
    __shared__ unsigned xs[64 * 68];  // 64 rows x 68 dwords (128 bf16 + pad)
    int tid = threadIdx.x;
    if (blockIdx.x == 0) {
        for (int i = tid; i < 2048; i += 256) sums8[i] = 0.f;
    }
    int r0 = blockIdx.x * 64;
    const float4* x4 = (const float4*)x;
#pragma unroll
    for (int it = 0; it < 8; ++it) {
        int i = tid + (it << 8);
        int r = i >> 5, c4 = i & 31;
        float4 v = {0.f, 0.f, 0.f, 0.f};
        if (r0 + r < N_NODES) v = x4[(size_t)(r0 + r) * 32 + c4];
        xs[r * 68 + c4 * 2]     = pack_bf16x2(v.x, v.y);
        xs[r * 68 + c4 * 2 + 1] = pack_bf16x2(v.z, v.w);
    }
    __syncthreads();
    int wave = tid >> 6, lane = tid & 63;
    int r0w = r0 + wave * 16;
    if (r0w >= N_NODES) return;
    int m = lane & 15, q = lane >> 4;
    bf16x8 afrag[4];
#pragma unroll
    for (int kt = 0; kt < 4; ++kt)
        afrag[kt] = *(const bf16x8*)&xs[(wave * 16 + m) * 68 + kt * 16 + q * 4];
    const uint4* B4 = (const uint4*)WTn;
    f32x4 acc[8];
#pragma unroll
    for (int nt = 0; nt < 8; ++nt)
        acc[nt][0] = acc[nt][1] = acc[nt][2] = acc[nt][3] = 0.f;
#pragma unroll
    for (int nt = 0; nt < 8; ++nt) {
#pragma unroll
        for (int kt = 0; kt < 4; ++kt) {
            uint4 braw = B4[(nt * 4 + kt) * 64 + lane];   // coalesced 1 KB/instr
            bf16x8 bfrag = __builtin_bit_cast(bf16x8, braw);
            acc[nt] = __builtin_amdgcn_mfma_f32_16x16x32_bf16(afrag[kt], bfrag, acc[nt], 0, 0, 0);
        }
    }
    int rb = r0w + q * 4;
    float dv[4];
#pragma unroll
    for (int reg = 0; reg < 4; ++reg) dv[reg] = rsqrtf((float)cnt[rb + reg] + 1.f);
#pragma unroll
    for (int nt = 0; nt < 8; ++nt) {
        int cbase = nt * 16 + m;
#pragma unroll
        for (int reg = 0; reg < 4; ++reg)
            g[(size_t)(rb + reg) * C + cbase] = bf16_1(acc[nt][reg] * dv[reg]);
    }
}

// ---- gather + fused BN stats: grid-stride, one wave per node per iter;
//      16 channel-lanes x 4 source-slots; per-block LDS channel partials
//      flushed to 8-sliced sums8 (low atomic contention). ----
#define ACC8(v) { a[0]+=blo(v.x); a[1]+=bhi(v.x); a[2]+=blo(v.y); a[3]+=bhi(v.y); \
                  a[4]+=blo(v.z); a[5]+=bhi(v.z); a[6]+=blo(v.w); a[7]+=bhi(v.w); }
__global__ void __launch_bounds__(512) k_gather(const int* __restrict__ offs,
                                                const unsigned short* __restrict__ srcs,
                                                const uint4* __restrict__ g4,
                                                unsigned* __restrict__ aggh,
                                                float* __restrict__ sums8) {
    __shared__ float lsA[8][32][4], lsQ[8][32][4];
    int tid = threadIdx.x;
    int lane = tid & 63, wid = tid >> 6;
    int l = lane & 15, q = lane >> 4;
    float sA[4] = {0.f, 0.f, 0.f, 0.f}, sQ[4] = {0.f, 0.f, 0.f, 0.f};
    int gw = blockIdx.x * 8 + wid;
    for (int node = gw; node < N_NODES; node += GATHER_WAVES) {
        int beg = offs[node], end = offs[node + 1];
        float a[8];
        if (q == 0) {
            uint4 u = g4[(size_t)node * 16 + l];  // self-loop term
            a[0]=blo(u.x); a[1]=bhi(u.x); a[2]=blo(u.y); a[3]=bhi(u.y);
            a[4]=blo(u.z); a[5]=bhi(u.z); a[6]=blo(u.w); a[7]=bhi(u.w);
        } else {
#pragma unroll
            for (int i = 0; i < 8; ++i) a[i] = 0.f;
        }
        for (int base = beg; base < end; base += 64) {
            int nb = end - base; if (nb > 64) nb = 64;
            int sv = (base + lane < end) ? (int)srcs[base + lane] : 0;
            int j0 = 0;
            for (; j0 + 16 <= nb; j0 += 16) {  // full groups: 4 loads in flight/lane
                int i0 = j0 + q;
                int s0 = __shfl(sv, i0, 64);
                int s1 = __shfl(sv, i0 + 4, 64);
                int s2 = __shfl(sv, i0 + 8, 64);
                int s3 = __shfl(sv, i0 + 12, 64);
                uint4 v0 = g4[(size_t)s0 * 16 + l];
                uint4 v1 = g4[(size_t)s1 * 16 + l];
                uint4 v2 = g4[(size_t)s2 * 16 + l];
                uint4 v3 = g4[(size_t)s3 * 16 + l];
                ACC8(v0) ACC8(v1) ACC8(v2) ACC8(v3)
            }
            if (j0 < nb) {  // tail group
#pragma unroll
                for (int k = 0; k < 4; ++k) {
                    int idx = j0 + q + 4 * k;
                    int s = __shfl(sv, idx, 64);
                    if (idx < nb) { uint4 v = g4[(size_t)s * 16 + l]; ACC8(v) }
                }
            }
        }
#pragma unroll
        for (int i = 0; i < 8; ++i) {
            a[i] += __shfl_xor(a[i], 16, 64);
            a[i] += __shfl_xor(a[i], 32, 64);
        }
        float dt = rsqrtf((float)(end - beg) + 1.f);
        if (q < 2) {
            float f0 = a[q * 4 + 0] * dt, f1 = a[q * 4 + 1] * dt;
            float f2 = a[q * 4 + 2] * dt, f3 = a[q * 4 + 3] * dt;
            sA[0] += f0; sQ[0] += f0 * f0;
            sA[1] += f1; sQ[1] += f1 * f1;
            sA[2] += f2; sQ[2] += f2 * f2;
            sA[3] += f3; sQ[3] += f3 * f3;
            uint2 pv; pv.x = pack_f16x2(f0, f1); pv.y = pack_f16x2(f2, f3);
            *(uint2*)(aggh + (size_t)node * 64 + l * 4 + q * 2) = pv;
        }
    }
    if (q < 2) {
#pragma unroll
        for (int i = 0; i < 4; ++i) {
            lsA[wid][l * 2 + q][i] = sA[i];
            lsQ[wid][l * 2 + q][i] = sQ[i];
        }
    }
    __syncthreads();
    if (tid < 128) {
        int ch = tid;
        int ll = ch >> 3, qq = (ch >> 2) & 1, ii = ch & 3;
        float s = 0.f, sq = 0.f;
#pragma unroll
        for (int wd = 0; wd < 8; ++wd) {
            s  += lsA[wd][ll * 2 + qq][ii];
            sq += lsQ[wd][ll * 2 + qq][ii];
        }
        int slice = (blockIdx.x & 7) * 256;
        atomicAdd(&sums8[slice + ch], s);
        atomicAdd(&sums8[slice + 128 + ch], sq);
    }
}

// ---- y = relu(aggh*scale + shift) -> f32 out; bias cancels in BN ----
__global__ void __launch_bounds__(256) k_final(const unsigned* __restrict__ aggh,
                                               float* __restrict__ out,
                                               const float* __restrict__ sums8,
                                               const float* __restrict__ gamma,
                                               const float* __restrict__ beta) {
    __shared__ float sc_s[C], sh_s[C];
    int tid = threadIdx.x;
    if (tid < C) {
        float s = 0.f, sq = 0.f;
#pragma unroll
        for (int k = 0; k < 8; ++k) {
            s  += sums8[k * 256 + tid];
            sq += sums8[k * 256 + 128 + tid];
        }
        float mean = s * (1.0f / N_NODES);
        float var = sq * (1.0f / N_NODES) - mean * mean;
        float sc = gamma[tid] * rsqrtf(var + BN_EPS);
        sc_s[tid] = sc;
        sh_s[tid] = beta[tid] - mean * sc;
    }
    __syncthreads();
    int i = blockIdx.x * 256 + tid;          // uint4 index over aggh, N*16 total
    uint4 v = ((const uint4*)aggh)[i];
    int c = (i & 15) * 8;
    float4 o0, o1;
    o0.x = fmaxf(f16lo(v.x) * sc_s[c+0] + sh_s[c+0], 0.f);
    o0.y = fmaxf(f16hi(v.x) * sc_s[c+1] + sh_s[c+1], 0.f);
    o0.z = fmaxf(f16lo(v.y) * sc_s[c+2] + sh_s[c+2], 0.f);
    o0.w = fmaxf(f16hi(v.y) * sc_s[c+3] + sh_s[c+3], 0.f);
    o1.x = fmaxf(f16lo(v.z) * sc_s[c+4] + sh_s[c+4], 0.f);
    o1.y = fmaxf(f16hi(v.z) * sc_s[c+5] + sh_s[c+5], 0.f);
    o1.z = fmaxf(f16lo(v.w) * sc_s[c+6] + sh_s[c+6], 0.f);
    o1.w = fmaxf(f16hi(v.w) * sc_s[c+7] + sh_s[c+7], 0.f);
    float4* o = (float4*)(out + (size_t)i * 8);
    o[0] = o0; o[1] = o1;
}

extern "C" void kernel_launch(void* const* d_in, const int* in_sizes, int n_in,
                              void* d_out, int out_size, void* d_ws, size_t ws_size,
                              hipStream_t stream) {
    const float* x     = (const float*)d_in[0];
    const float* W     = (const float*)d_in[1];
    // d_in[2] = bias: cancels in BatchNorm, unused
    const float* gamma = (const float*)d_in[3];
    const float* beta  = (const float*)d_in[4];
    const int*   eidx  = (const int*)d_in[5];
    const int* row = eidx;
    const int* col = eidx + N_EDGES;

    float* out = (float*)d_out;  // [N, C] f32

    // workspace layout (all 16B-aligned)
    unsigned* g      = (unsigned*)d_ws;                          // [N*64] bf16x2 rows (12.8 MB)
    unsigned* aggh   = g + (size_t)N_NODES * 64;                 // [N*64] f16x2 rows (12.8 MB)
    unsigned* bEdges = aggh + (size_t)N_NODES * 64;              // [A_BLOCKS*EPB] (3.2 MB)
    unsigned* WTn    = bEdges + (size_t)A_BLOCKS * EPB;          // [8192] bf16x2 (W, MFMA-B layout)
    unsigned short* srcs = (unsigned short*)(WTn + 8192);        // [E] u16 (1.6 MB)
    int*   cnt    = (int*)(srcs + N_EDGES);                      // [N]
    int*   offs   = cnt + N_NODES;                               // [N+1] (+3 pad)
    float* sums8  = (float*)(offs + N_NODES + 4);                // [8*256] sliced BN accum (zeroed by gemm b0)
    int*   bOffsT = (int*)(sums8 + 2048);                        // [(NBUCK+1)*A_BLOCKS] (613 KB)

    k_scat<<<A_BLOCKS, 256, 0, stream>>>(row, col, bEdges, bOffsT, W, WTn);
    k_bsort<<<NBUCK, 256, 0, stream>>>(bEdges, bOffsT, offs, cnt, srcs);
    k_gemm<<<(N_NODES + 63) / 64, 256, 0, stream>>>(x, WTn, cnt, (unsigned short*)g, sums8);
    k_gather<<<GATHER_BLOCKS, 512, 0, stream>>>(offs, srcs, (const uint4*)g, aggh, sums8);
    k_final<<<N_NODES * 16 / 256, 256, 0, stream>>>(aggh, out, sums8, gamma, beta);
}

// Round 6
// 153.432 us; speedup vs baseline: 1.6651x; 1.0592x over previous
//
#include <hip/hip_runtime.h>

#define N_NODES 50000
#define N_EDGES 800000
#define C 128
#define BN_EPS 1e-5f
#define BSHIFT 7                              // 128 nodes per bucket
#define NBUCK ((N_NODES + 127) >> BSHIFT)     // 391
#define EPB 2048                              // edges per scat block
#define A_BLOCKS ((N_EDGES + EPB - 1) / EPB)  // 391
#define EBUF 2560                             // per-bucket staging cap (mean 2046, +11 sigma)
#define GEMM_BLOCKS ((N_NODES + 63) / 64)     // 782
#define GATHER_BLOCKS 512
#define GATHER_WAVES (GATHER_BLOCKS * 8)      // 4096

typedef __attribute__((ext_vector_type(8))) short bf16x8;
typedef __attribute__((ext_vector_type(4))) float f32x4;

__device__ __forceinline__ unsigned pack_bf16x2(float a, float b) {
    unsigned ua = __float_as_uint(a);
    ua = (ua + 0x7FFFu + ((ua >> 16) & 1u)) >> 16;   // RNE
    unsigned ub = __float_as_uint(b);
    ub = (ub + 0x7FFFu + ((ub >> 16) & 1u)) >> 16;
    return ua | (ub << 16);
}

__device__ __forceinline__ unsigned short bf16_1(float a) {
    unsigned u = __float_as_uint(a);
    return (unsigned short)((u + 0x7FFFu + ((u >> 16) & 1u)) >> 16);
}

__device__ __forceinline__ float blo(unsigned u) { return __uint_as_float(u << 16); }
__device__ __forceinline__ float bhi(unsigned u) { return __uint_as_float(u & 0xFFFF0000u); }

__device__ __forceinline__ unsigned pack_f16x2(float a, float b) {
    _Float16 ha = (_Float16)a, hb = (_Float16)b;
    return (unsigned)__builtin_bit_cast(unsigned short, ha) |
           ((unsigned)__builtin_bit_cast(unsigned short, hb) << 16);
}
__device__ __forceinline__ float f16lo(unsigned u) {
    return (float)__builtin_bit_cast(_Float16, (unsigned short)(u & 0xFFFFu));
}
__device__ __forceinline__ float f16hi(unsigned u) {
    return (float)__builtin_bit_cast(_Float16, (unsigned short)(u >> 16));
}

// ---- dispatch 1: per-block counting sort of 2048 edges into OWN bEdges region,
//      grouped by bucket; exclusive per-bucket offsets -> bOffsT[b][w].
//      Register shfl-scan. No device atomics. Extra block (A_BLOCKS) builds
//      the MFMA-B-layout bf16 W and zeroes the BN accumulators. ----
__global__ void __launch_bounds__(256) k_scat(const int* __restrict__ row,
                                              const int* __restrict__ col,
                                              unsigned* __restrict__ bEdges,
                                              int* __restrict__ bOffsT,
                                              const float* __restrict__ W,
                                              unsigned* __restrict__ WTn,
                                              float* __restrict__ sums8) {
    int tid = threadIdx.x, w = blockIdx.x;
    if (w == A_BLOCKS) {
        // WTn dword i = ((nt*4+kt)*64 + q*16+m)*4 + j  holds
        //   pack( W[kt*32+q*8+2j][nt*16+m], W[kt*32+q*8+2j+1][nt*16+m] )
#pragma unroll
        for (int it = 0; it < 32; ++it) {
            int i = tid + (it << 8);
            int j = i & 3, l = (i >> 2) & 63, kt = (i >> 8) & 3, nt = i >> 10;
            int m = l & 15, q = l >> 4;
            int kr = kt * 32 + q * 8 + 2 * j;
            int n = nt * 16 + m;
            WTn[i] = pack_bf16x2(W[kr * C + n], W[(kr + 1) * C + n]);
        }
        for (int i = tid; i < 2048; i += 256) sums8[i] = 0.f;
        return;
    }
    __shared__ int hist[NBUCK];
    __shared__ int wsum[8];
    int lane = tid & 63, wid = tid >> 6;
    for (int i = tid; i < NBUCK; i += 256) hist[i] = 0;
    __syncthreads();
    int e0 = w * EPB;
    int nE = N_EDGES - e0; if (nE > EPB) nE = EPB;
    int myc[8], myr[8];
#pragma unroll
    for (int k = 0; k < 8; ++k) {
        int idx = tid + (k << 8);
        bool ok = idx < nE;
        myc[k] = ok ? col[e0 + idx] : -1;
        myr[k] = ok ? row[e0 + idx] : 0;
        if (ok) atomicAdd(&hist[myc[k] >> BSHIFT], 1);
    }
    __syncthreads();
    // register scan over 391 buckets: positions tid and tid+256
    int v0 = hist[tid];
    int v1 = (tid + 256 < NBUCK) ? hist[tid + 256] : 0;
    int s0 = v0, s1 = v1;
#pragma unroll
    for (int d = 1; d < 64; d <<= 1) {
        int u0 = __shfl_up(s0, d, 64);
        int u1 = __shfl_up(s1, d, 64);
        if (lane >= d) { s0 += u0; s1 += u1; }
    }
    if (lane == 63) { wsum[wid] = s0; wsum[4 + wid] = s1; }
    __syncthreads();
    int tot0 = wsum[0] + wsum[1] + wsum[2] + wsum[3];
    int p0 = 0, p1 = tot0;
    for (int i = 0; i < wid; ++i) { p0 += wsum[i]; p1 += wsum[4 + i]; }
    int exc0 = p0 + s0 - v0;
    int exc1 = p1 + s1 - v1;
    bOffsT[tid * A_BLOCKS + w] = exc0;
    if (tid + 256 < NBUCK) bOffsT[(tid + 256) * A_BLOCKS + w] = exc1;
    if (tid == 0) bOffsT[NBUCK * A_BLOCKS + w] = nE;
    hist[tid] = exc0;                                   // cursors
    if (tid + 256 < NBUCK) hist[tid + 256] = exc1;
    __syncthreads();
#pragma unroll
    for (int k = 0; k < 8; ++k) {
        if (myc[k] >= 0) {
            int b = myc[k] >> BSHIFT;
            int r = atomicAdd(&hist[b], 1);  // LDS only
            bEdges[(size_t)w * EPB + r] = (unsigned)myr[k] | ((unsigned)myc[k] << 16);
        }
    }
}

// ---- dispatch 2: bsort (blocks 0..390) | gemm (blocks 391..1172).
//      Both depend only on k_scat; gemm writes UNSCALED bf16(x@W) (dinv
//      deferred to gather), so it needs no sort output. LDS unioned. ----
__global__ void __launch_bounds__(256) k_mid(const unsigned* __restrict__ bEdges,
                                             const int* __restrict__ bOffsT,
                                             int* __restrict__ offs,
                                             float* __restrict__ dinvArr,
                                             unsigned short* __restrict__ srcs,
                                             const float* __restrict__ x,
                                             const unsigned* __restrict__ WTn,
                                             unsigned short* __restrict__ g16) {
    __shared__ __align__(16) unsigned sm[4352];   // union: bsort 13.9KB | gemm 17.4KB
    __shared__ int wsum[12];
    __shared__ int wtot;
    int tid = threadIdx.x;
    int lane = tid & 63, wid = tid >> 6;
    if (blockIdx.x < NBUCK) {
        // ---- bsort bucket b ----
        const int b = blockIdx.x;
        int* sS = (int*)sm;                        // [391]
        int* sO = (int*)sm + 392;                  // [392]
        unsigned* ebuf = sm + 792;                 // [EBUF]
        int* h = (int*)(sm + 792 + EBUF);          // [128]
        int i1 = tid + 256;
        int st0 = bOffsT[b * A_BLOCKS + tid];
        int v0 = bOffsT[(b + 1) * A_BLOCKS + tid] - st0;
        int st1 = 0, v1 = 0;
        if (i1 < A_BLOCKS) {
            st1 = bOffsT[b * A_BLOCKS + i1];
            v1 = bOffsT[(b + 1) * A_BLOCKS + i1] - st1;
        }
        sS[tid] = st0;
        if (i1 < A_BLOCKS) sS[i1] = st1;
        if (tid < 128) h[tid] = 0;
        // e0 = sum of starts; scan of counts -> sO
        int ep = st0 + st1;
        int s0 = v0, s1 = v1;
#pragma unroll
        for (int d = 1; d < 64; d <<= 1) {
            int u0 = __shfl_up(s0, d, 64);
            int u1 = __shfl_up(s1, d, 64);
            if (lane >= d) { s0 += u0; s1 += u1; }
            ep += __shfl_xor(ep, d, 64);
        }
        if (lane == 63) { wsum[wid] = s0; wsum[4 + wid] = s1; }
        if (lane == 0) wsum[8 + wid] = ep;
        __syncthreads();
        int tot0 = wsum[0] + wsum[1] + wsum[2] + wsum[3];
        int tot1 = wsum[4] + wsum[5] + wsum[6] + wsum[7];
        int e0 = wsum[8] + wsum[9] + wsum[10] + wsum[11];
        int p0 = 0, p1 = tot0;
        for (int i = 0; i < wid; ++i) { p0 += wsum[i]; p1 += wsum[4 + i]; }
        sO[tid] = p0 + s0 - v0;
        if (i1 < A_BLOCKS) sO[i1] = p1 + s1 - v1;
        if (tid == 0) sO[A_BLOCKS] = tot0 + tot1;
        __syncthreads();
        int c = sO[A_BLOCKS];
        if (c > EBUF) c = EBUF;  // statistically impossible; memory-safety only
        // stage: each thread copies its segments sequentially (offsets known)
        for (int seg = tid; seg < A_BLOCKS; seg += 256) {
            int o = sO[seg];
            int n = sO[seg + 1] - o;
            const unsigned* srcp = bEdges + (size_t)seg * EPB + sS[seg];
            for (int k = 0; k < n; ++k) {
                int dp = o + k;
                if (dp < EBUF) ebuf[dp] = srcp[k];
            }
        }
        __syncthreads();
        int n0 = b << BSHIFT;
        int nn = N_NODES - n0; if (nn > 128) nn = 128;
        for (int e = tid; e < c; e += 256)
            atomicAdd(&h[(int)(ebuf[e] >> 16) - n0], 1);
        __syncthreads();
        int v = 0, sc = 0;
        if (tid < 128) {
            int ln = tid & 63;
            v = h[tid];
            sc = v;
#pragma unroll
            for (int d = 1; d < 64; d <<= 1) {
                int u = __shfl_up(sc, d, 64);
                if (ln >= d) sc += u;
            }
            if (tid == 63) wtot = sc;
        }
        __syncthreads();
        if (tid < 128) {
            int ex = sc - v + ((tid >= 64) ? wtot : 0);
            if (tid < nn) {
                offs[n0 + tid] = e0 + ex;
                dinvArr[n0 + tid] = rsqrtf((float)v + 1.f);
            }
            h[tid] = ex;  // reuse as cursor
        }
        __syncthreads();
        for (int e = tid; e < c; e += 256) {
            unsigned pe = ebuf[e];
            int r = atomicAdd(&h[(int)(pe >> 16) - n0], 1);
            srcs[e0 + r] = (unsigned short)(pe & 0xFFFFu);
        }
        if (b == NBUCK - 1 && tid == 0) offs[N_NODES] = N_EDGES;
    } else {
        // ---- gemm unit: 64 rows, unscaled g = bf16(x@W) ----
        unsigned* xs = sm;  // [64*68]
        int r0 = (blockIdx.x - NBUCK) * 64;
        const float4* x4 = (const float4*)x;
#pragma unroll
        for (int it = 0; it < 8; ++it) {
            int i = tid + (it << 8);
            int r = i >> 5, c4 = i & 31;
            float4 v = {0.f, 0.f, 0.f, 0.f};
            if (r0 + r < N_NODES) v = x4[(size_t)(r0 + r) * 32 + c4];
            xs[r * 68 + c4 * 2]     = pack_bf16x2(v.x, v.y);
            xs[r * 68 + c4 * 2 + 1] = pack_bf16x2(v.z, v.w);
        }
        __syncthreads();
        int r0w = r0 + wid * 16;
        if (r0w >= N_NODES) return;
        int m = lane & 15, q = lane >> 4;
        bf16x8 afrag[4];
#pragma unroll
        for (int kt = 0; kt < 4; ++kt)
            afrag[kt] = *(const bf16x8*)&xs[(wid * 16 + m) * 68 + kt * 16 + q * 4];
        const uint4* B4 = (const uint4*)WTn;
        f32x4 acc[8];
#pragma unroll
        for (int nt = 0; nt < 8; ++nt)
            acc[nt][0] = acc[nt][1] = acc[nt][2] = acc[nt][3] = 0.f;
#pragma unroll
        for (int nt = 0; nt < 8; ++nt) {
#pragma unroll
            for (int kt = 0; kt < 4; ++kt) {
                uint4 braw = B4[(nt * 4 + kt) * 64 + lane];   // coalesced 1 KB/instr
                bf16x8 bfrag = __builtin_bit_cast(bf16x8, braw);
                acc[nt] = __builtin_amdgcn_mfma_f32_16x16x32_bf16(afrag[kt], bfrag, acc[nt], 0, 0, 0);
            }
        }
        int rb = r0w + q * 4;
#pragma unroll
        for (int nt = 0; nt < 8; ++nt) {
            int cbase = nt * 16 + m;
#pragma unroll
            for (int reg = 0; reg < 4; ++reg)
                g16[(size_t)(rb + reg) * C + cbase] = bf16_1(acc[nt][reg]);
        }
    }
}

// ---- dispatch 3: gather + fused BN stats. One wave per node per iter;
//      16 channel-lanes x 4 source-slots; per-source dinv FMA (deferred
//      norm); per-block LDS partials -> 8-sliced sums8. ----
#define ACC8S(v, d) { a[0]+=blo(v.x)*d; a[1]+=bhi(v.x)*d; a[2]+=blo(v.y)*d; a[3]+=bhi(v.y)*d; \
                      a[4]+=blo(v.z)*d; a[5]+=bhi(v.z)*d; a[6]+=blo(v.w)*d; a[7]+=bhi(v.w)*d; }
__global__ void __launch_bounds__(512) k_gather(const int* __restrict__ offs,
                                                const unsigned short* __restrict__ srcs,
                                                const uint4* __restrict__ g4,
                                                const float* __restrict__ dinvArr,
                                                unsigned* __restrict__ aggh,
                                                float* __restrict__ sums8) {
    __shared__ float lsA[8][32][4], lsQ[8][32][4];
    int tid = threadIdx.x;
    int lane = tid & 63, wid = tid >> 6;
    int l = lane & 15, q = lane >> 4;
    float sA[4] = {0.f, 0.f, 0.f, 0.f}, sQ[4] = {0.f, 0.f, 0.f, 0.f};
    int gw = blockIdx.x * 8 + wid;
    for (int node = gw; node < N_NODES; node += GATHER_WAVES) {
        int beg = offs[node], end = offs[node + 1];
        float dt = dinvArr[node];
        float a[8];
        if (q == 0) {
            uint4 u = g4[(size_t)node * 16 + l];  // self-loop: *dt here, *dt again at end
            a[0]=blo(u.x)*dt; a[1]=bhi(u.x)*dt; a[2]=blo(u.y)*dt; a[3]=bhi(u.y)*dt;
            a[4]=blo(u.z)*dt; a[5]=bhi(u.z)*dt; a[6]=blo(u.w)*dt; a[7]=bhi(u.w)*dt;
        } else {
#pragma unroll
            for (int i = 0; i < 8; ++i) a[i] = 0.f;
        }
        for (int base = beg; base < end; base += 64) {
            int nb = end - base; if (nb > 64) nb = 64;
            int sv = (base + lane < end) ? (int)srcs[base + lane] : 0;
            int j0 = 0;
            for (; j0 + 16 <= nb; j0 += 16) {  // full groups: 4 loads in flight/lane
                int i0 = j0 + q;
                int s0 = __shfl(sv, i0, 64);
                int s1 = __shfl(sv, i0 + 4, 64);
                int s2 = __shfl(sv, i0 + 8, 64);
                int s3 = __shfl(sv, i0 + 12, 64);
                float d0 = dinvArr[s0], d1 = dinvArr[s1], d2 = dinvArr[s2], d3 = dinvArr[s3];
                uint4 v0 = g4[(size_t)s0 * 16 + l];
                uint4 v1 = g4[(size_t)s1 * 16 + l];
                uint4 v2 = g4[(size_t)s2 * 16 + l];
                uint4 v3 = g4[(size_t)s3 * 16 + l];
                ACC8S(v0, d0) ACC8S(v1, d1) ACC8S(v2, d2) ACC8S(v3, d3)
            }
            if (j0 < nb) {  // tail group
#pragma unroll
                for (int k = 0; k < 4; ++k) {
                    int idx = j0 + q + 4 * k;
                    int s = __shfl(sv, idx, 64);
                    if (idx < nb) {
                        float dd = dinvArr[s];
                        uint4 v = g4[(size_t)s * 16 + l];
                        ACC8S(v, dd)
                    }
                }
            }
        }
#pragma unroll
        for (int i = 0; i < 8; ++i) {
            a[i] += __shfl_xor(a[i], 16, 64);
            a[i] += __shfl_xor(a[i], 32, 64);
        }
        if (q < 2) {
            float f0 = a[q * 4 + 0] * dt, f1 = a[q * 4 + 1] * dt;
            float f2 = a[q * 4 + 2] * dt, f3 = a[q * 4 + 3] * dt;
            sA[0] += f0; sQ[0] += f0 * f0;
            sA[1] += f1; sQ[1] += f1 * f1;
            sA[2] += f2; sQ[2] += f2 * f2;
            sA[3] += f3; sQ[3] += f3 * f3;
            uint2 pv; pv.x = pack_f16x2(f0, f1); pv.y = pack_f16x2(f2, f3);
            *(uint2*)(aggh + (size_t)node * 64 + l * 4 + q * 2) = pv;
        }
    }
    if (q < 2) {
#pragma unroll
        for (int i = 0; i < 4; ++i) {
            lsA[wid][l * 2 + q][i] = sA[i];
            lsQ[wid][l * 2 + q][i] = sQ[i];
        }
    }
    __syncthreads();
    if (tid < 128) {
        int ll = tid >> 3, qq = (tid >> 2) & 1, ii = tid & 3;
        float s = 0.f, sq = 0.f;
#pragma unroll
        for (int wd = 0; wd < 8; ++wd) {
            s  += lsA[wd][ll * 2 + qq][ii];
            sq += lsQ[wd][ll * 2 + qq][ii];
        }
        int slice = (blockIdx.x & 7) * 256;
        atomicAdd(&sums8[slice + tid], s);
        atomicAdd(&sums8[slice + 128 + tid], sq);
    }
}

// ---- dispatch 4: y = relu(aggh*scale + shift) -> f32 out; bias cancels in BN ----
__global__ void __launch_bounds__(256) k_final(const unsigned* __restrict__ aggh,
                                               float* __restrict__ out,
                                               const float* __restrict__ sums8,
                                               const float* __restrict__ gamma,
                                               const float* __restrict__ beta) {
    __shared__ float sc_s[C], sh_s[C];
    int tid = threadIdx.x;
    if (tid < C) {
        float s = 0.f, sq = 0.f;
#pragma unroll
        for (int k = 0; k < 8; ++k) {
            s  += sums8[k * 256 + tid];
            sq += sums8[k * 256 + 128 + tid];
        }
        float mean = s * (1.0f / N_NODES);
        float var = sq * (1.0f / N_NODES) - mean * mean;
        float sc = gamma[tid] * rsqrtf(var + BN_EPS);
        sc_s[tid] = sc;
        sh_s[tid] = beta[tid] - mean * sc;
    }
    __syncthreads();
    int i = blockIdx.x * 256 + tid;          // uint4 index over aggh, N*16 total
    uint4 v = ((const uint4*)aggh)[i];
    int c = (i & 15) * 8;
    float4 o0, o1;
    o0.x = fmaxf(f16lo(v.x) * sc_s[c+0] + sh_s[c+0], 0.f);
    o0.y = fmaxf(f16hi(v.x) * sc_s[c+1] + sh_s[c+1], 0.f);
    o0.z = fmaxf(f16lo(v.y) * sc_s[c+2] + sh_s[c+2], 0.f);
    o0.w = fmaxf(f16hi(v.y) * sc_s[c+3] + sh_s[c+3], 0.f);
    o1.x = fmaxf(f16lo(v.z) * sc_s[c+4] + sh_s[c+4], 0.f);
    o1.y = fmaxf(f16hi(v.z) * sc_s[c+5] + sh_s[c+5], 0.f);
    o1.z = fmaxf(f16lo(v.w) * sc_s[c+6] + sh_s[c+6], 0.f);
    o1.w = fmaxf(f16hi(v.w) * sc_s[c+7] + sh_s[c+7], 0.f);
    float4* o = (float4*)(out + (size_t)i * 8);
    o[0] = o0; o[1] = o1;
}

extern "C" void kernel_launch(void* const* d_in, const int* in_sizes, int n_in,
                              void* d_out, int out_size, void* d_ws, size_t ws_size,
                              hipStream_t stream) {
    const float* x     = (const float*)d_in[0];
    const float* W     = (const float*)d_in[1];
    // d_in[2] = bias: cancels in BatchNorm, unused
    const float* gamma = (const float*)d_in[3];
    const float* beta  = (const float*)d_in[4];
    const int*   eidx  = (const int*)d_in[5];
    const int* row = eidx;
    const int* col = eidx + N_EDGES;

    float* out = (float*)d_out;  // [N, C] f32

    // workspace layout (all 16B-aligned)
    unsigned* g      = (unsigned*)d_ws;                          // [N*64] bf16x2 rows (12.8 MB)
    unsigned* aggh   = g + (size_t)N_NODES * 64;                 // [N*64] f16x2 rows (12.8 MB)
    unsigned* bEdges = aggh + (size_t)N_NODES * 64;              // [A_BLOCKS*EPB] (3.2 MB)
    unsigned* WTn    = bEdges + (size_t)A_BLOCKS * EPB;          // [8192] bf16x2 (W, MFMA-B layout)
    unsigned short* srcs = (unsigned short*)(WTn + 8192);        // [E] u16 (1.6 MB)
    int*   offs    = (int*)(srcs + N_EDGES);                     // [N+1] (+3 pad)
    float* dinvArr = (float*)(offs + N_NODES + 4);               // [N]
    float* sums8   = dinvArr + N_NODES;                          // [8*256] sliced BN accum
    int*   bOffsT  = (int*)(sums8 + 2048);                       // [(NBUCK+1)*A_BLOCKS] (613 KB)

    k_scat<<<A_BLOCKS + 1, 256, 0, stream>>>(row, col, bEdges, bOffsT, W, WTn, sums8);
    k_mid<<<NBUCK + GEMM_BLOCKS, 256, 0, stream>>>(bEdges, bOffsT, offs, dinvArr, srcs,
                                                   x, WTn, (unsigned short*)g);
    k_gather<<<GATHER_BLOCKS, 512, 0, stream>>>(offs, srcs, (const uint4*)g, dinvArr, aggh, sums8);
    k_final<<<N_NODES * 16 / 256, 256, 0, stream>>>(aggh, out, sums8, gamma, beta);
}